// Round 7
// baseline (931.067 us; speedup 1.0000x reference)
//
#include <hip/hip_runtime.h>
#include <climits>
#include <cstdint>

#define NV    2048
#define MAXE  344
#define HSIZE 8192
#define HMASK 8191
#define BIGK  LLONG_MAX
#define K3MAX 343
#define MAXP  256

__device__ __forceinline__ unsigned hashk(long long k) {
  unsigned long long x = (unsigned long long)k * 0x9E3779B97F4A7C15ull;
  return (unsigned)(x >> 51) & HMASK;
}

// ---------------- init ----------------
__global__ __launch_bounds__(256) void k_init(const float* __restrict__ vf,
    const int* __restrict__ coors, int* __restrict__ cA, float* __restrict__ fA,
    int* __restrict__ nact)
{
  int i = blockIdx.x * 256 + threadIdx.x;
  if (i == 0) nact[0] = NV;
  if (i >= NV) return;
  cA[i*4+0] = coors[i*4+0];
  cA[i*4+1] = coors[i*4+1];
  cA[i*4+2] = coors[i*4+2];
  cA[i*4+3] = coors[i*4+3];
  fA[i] = vf[i];
}

// ---------------- hash ----------------
__global__ __launch_bounds__(256) void k_hclear(long long* __restrict__ hk,
    int* __restrict__ ocnt)
{
  int i = blockIdx.x * 256 + threadIdx.x;
  if (i < HSIZE) hk[i] = -1LL;
  if (i < K3MAX) ocnt[i] = 0;
}

__global__ __launch_bounds__(256) void k_hinsert(const int* __restrict__ c,
    long long* __restrict__ hk, int* __restrict__ hv, const int* __restrict__ nactp,
    int D, int H, int Wd)
{
  int i = blockIdx.x * 256 + threadIdx.x;
  if (i >= NV || i >= *nactp) return;
  long long key = (((long long)c[i*4+0]*D + c[i*4+1])*H + c[i*4+2])*(long long)Wd + c[i*4+3];
  unsigned h = hashk(key);
  while (true) {
    unsigned long long old = atomicCAS((unsigned long long*)&hk[h], ~0ull, (unsigned long long)key);
    if (old == ~0ull) { hv[h] = i; break; }
    h = (h + 1) & HMASK;
  }
}

// ---------------- neighbor hit lists (one wave per site), grouped by offset ----------------
template<int K>
__global__ __launch_bounds__(256) void k_hits(const int* __restrict__ c,
    const long long* __restrict__ hk, const int* __restrict__ hv,
    const int* __restrict__ nactp, int* __restrict__ pslot, int* __restrict__ cnt,
    int* __restrict__ ocnt, int* __restrict__ olist,
    int D, int H, int Wd)
{
  constexpr int K3 = K*K*K, R = K/2, CTR = K3/2;
  const int site = blockIdx.x * 4 + (threadIdx.x >> 6);
  const int lane = threadIdx.x & 63;
  const int nact = *nactp;
  if (site >= NV) return;
  if (site >= nact) { if (lane == 0) cnt[site] = 0; return; }
  const int b = c[site*4+0], d = c[site*4+1], hc = c[site*4+2], w = c[site*4+3];
  int base = 0;
  for (int o0 = 0; o0 < K3; o0 += 64) {
    const int o = o0 + lane;
    int j = -1;
    if (o < K3 && o != CTR) {
      const int dz = o/(K*K) - R, dy = (o/K)%K - R, dx = o%K - R;
      const int nd = d+dz, nh = hc+dy, nw = w+dx;
      if (nd >= 0 && nd < D && nh >= 0 && nh < H && nw >= 0 && nw < Wd) {
        const long long key = (((long long)b*D + nd)*H + nh)*(long long)Wd + nw;
        unsigned hs = hashk(key);
        while (true) {
          const long long kk = hk[hs];
          if (kk == -1LL) break;
          if (kk == key) { j = hv[hs]; break; }
          hs = (hs + 1) & HMASK;
        }
      }
    }
    const unsigned long long m = __ballot(j >= 0);
    if (j >= 0) {
      const int pos = __popcll(m & ((1ull << lane) - 1ull));
      const int p = atomicAdd(&ocnt[o], 1);
      int tag = -1;
      if (p < MAXP) { olist[o * MAXP + p] = (site << 12) | j; tag = (o << 8) | p; }
      pslot[site * MAXE + base + pos] = tag;
    }
    base += __popcll(m);
  }
  if (lane == 0) cnt[site] = base;
}

// ---------------- exclusive scan of per-offset hit counts -> compact slot bases ----------------
__global__ __launch_bounds__(512) void k_oscan(const int* __restrict__ ocnt,
    int* __restrict__ obase)
{
  __shared__ int s[512];
  const int t = threadIdx.x;
  const int v = (t < K3MAX) ? min(ocnt[t], MAXP) : 0;
  s[t] = v;
  __syncthreads();
  for (int d = 1; d < 512; d <<= 1) {
    const int x = (t >= d) ? s[t - d] : 0;
    __syncthreads();
    s[t] += x;
    __syncthreads();
  }
  if (t < K3MAX) obase[t] = s[t] - v;
}

// ---------------- center GEMM, CIN==1: outer product ----------------
template<int COUT>
__global__ __launch_bounds__(256) void k_gemm1(const float* __restrict__ f,
    const float* __restrict__ Wc, float* __restrict__ out)
{
  const int idx = blockIdx.x * 256 + threadIdx.x;
  if (idx >= NV * COUT) return;
  const int i = idx / COUT, c = idx - i * COUT;
  out[idx] = f[i] * Wc[c];
}

// ---------------- dense center GEMM: LDS-tiled, reg-prefetch double buffer ----------------
template<int CIN, int COUT>
__global__ __launch_bounds__(256) void k_gemm(const float* __restrict__ f,
    const float* __restrict__ Wc, float* __restrict__ out)
{
  constexpr int BN = (COUT < 128) ? COUT : 128;
  constexpr int NQ = BN / 4;
  constexpr int TY = 256 / NQ;
  constexpr int BM = 32;
  constexpr int MR = BM / TY;
  constexpr int KT = 32;
  constexpr int NT = CIN / KT;
  constexpr int NCB = COUT / BN;
  constexpr int WLPT = (KT * NQ) / 256;
  __shared__ float as[BM][KT + 1];
  __shared__ float ws[KT][BN];

  const int rb = blockIdx.x / NCB;
  const int cb = blockIdx.x - rb * NCB;
  const int row0 = rb * BM;
  const int col0 = cb * BN;
  const int tid = threadIdx.x;
  const int cq = tid % NQ;
  const int ty = tid / NQ;
  const int la_r = tid >> 3;
  const int la_q = tid & 7;

  const float* __restrict__ fA = f + (size_t)(row0 + la_r) * CIN + la_q * 4;
  const float* __restrict__ fW = Wc + col0;

  float4 aP, wP[WLPT];
  aP = *(const float4*)&fA[0];
  #pragma unroll
  for (int i = 0; i < WLPT; ++i) {
    const int idx = tid + i*256, k = idx / NQ, q = idx - k*NQ;
    wP[i] = *(const float4*)&fW[(size_t)k * COUT + q*4];
  }

  float4 acc[MR];
  #pragma unroll
  for (int i = 0; i < MR; ++i) { acc[i].x=0.f; acc[i].y=0.f; acc[i].z=0.f; acc[i].w=0.f; }

  for (int t = 0; t < NT; ++t) {
    as[la_r][la_q*4+0] = aP.x;
    as[la_r][la_q*4+1] = aP.y;
    as[la_r][la_q*4+2] = aP.z;
    as[la_r][la_q*4+3] = aP.w;
    #pragma unroll
    for (int i = 0; i < WLPT; ++i) {
      const int idx = tid + i*256, k = idx / NQ, q = idx - k*NQ;
      *(float4*)&ws[k][q*4] = wP[i];
    }
    __syncthreads();
    if (t + 1 < NT) {
      const int k0 = (t + 1) * KT;
      aP = *(const float4*)&fA[k0];
      #pragma unroll
      for (int i = 0; i < WLPT; ++i) {
        const int idx = tid + i*256, k = idx / NQ, q = idx - k*NQ;
        wP[i] = *(const float4*)&fW[(size_t)(k0 + k) * COUT + q*4];
      }
    }
    #pragma unroll
    for (int k = 0; k < KT; ++k) {
      const float4 wv = *(const float4*)&ws[k][cq*4];
      #pragma unroll
      for (int i = 0; i < MR; ++i) {
        const float av = as[ty*MR + i][k];
        acc[i].x = fmaf(av, wv.x, acc[i].x);
        acc[i].y = fmaf(av, wv.y, acc[i].y);
        acc[i].z = fmaf(av, wv.z, acc[i].z);
        acc[i].w = fmaf(av, wv.w, acc[i].w);
      }
    }
    __syncthreads();
  }
  #pragma unroll
  for (int i = 0; i < MR; ++i)
    *(float4*)&out[(size_t)(row0 + ty*MR + i) * COUT + col0 + cq*4] = acc[i];
}

// ---------------- legacy pgemm: used only for CIN==1 (layer 0), tiny ----------------
template<int CIN, int COUT>
__global__ __launch_bounds__(256) void k_pgemm(const float* __restrict__ f,
    const float* __restrict__ Wall, float* __restrict__ P,
    const int* __restrict__ ocnt, const int* __restrict__ obase,
    const int* __restrict__ olist)
{
  constexpr int SLOTCAP = (40*1024*1024) / (COUT*4);
  const int o = blockIdx.x;
  int m = ocnt[o];
  if (m == 0) return;
  if (m > MAXP) m = MAXP;
  const int sbase = obase[o];
  const int tid = threadIdx.x;
  const float* __restrict__ Wo = Wall + (size_t)o * (CIN*COUT);
  for (int p = 0; p < m; ++p) {
    const int j = olist[o*MAXP + p] & 0xFFF;
    const float fv = f[j];   // CIN == 1
    const int slot = sbase + p;
    if (slot < SLOTCAP && tid < COUT)
      P[(size_t)slot*COUT + tid] = fv * Wo[tid];
  }
}

// ---------------- per-offset gather-GEMM: P[slot] = f[j_slot] @ W[o] ----------------
// LDS-tiled, reg-prefetch double buffer; one writer per P row -> deterministic.
template<int CIN, int COUT>
__global__ __launch_bounds__(256) void k_pogemm(const float* __restrict__ f,
    const float* __restrict__ Wall, float* __restrict__ P,
    const int* __restrict__ ocnt, const int* __restrict__ obase,
    const int* __restrict__ olist)
{
  constexpr int BN = (COUT < 128) ? COUT : 128;
  constexpr int NQ = BN / 4;
  constexpr int TY = 256 / NQ;
  constexpr int BM = 32;
  constexpr int MR = BM / TY;
  constexpr int KT = 32;
  constexpr int NT = CIN / KT;
  constexpr int NCB = COUT / BN;
  constexpr int NRT = MAXP / BM;     // 8 row-tiles max
  constexpr int WLPT = (KT * NQ) / 256;
  constexpr int SLOTCAP = (40*1024*1024) / (COUT*4);
  __shared__ float as[BM][KT + 1];
  __shared__ float ws[KT][BN];

  const int o   = blockIdx.x / (NRT * NCB);
  const int rem = blockIdx.x - o * (NRT * NCB);
  const int rt  = rem / NCB;
  const int cb  = rem - rt * NCB;
  int m = ocnt[o];
  if (m > MAXP) m = MAXP;
  const int row0 = rt * BM;
  if (m == 0 || row0 >= m) return;
  const int sbase = obase[o];
  const int col0 = cb * BN;
  const int tid = threadIdx.x;
  const int cq = tid % NQ;
  const int ty = tid / NQ;
  const int la_r = tid >> 3;
  const int la_q = tid & 7;

  const int pA = row0 + la_r;
  const int jrow = olist[o*MAXP + ((pA < m) ? pA : row0)] & 0xFFF;
  const float* __restrict__ fA = f + (size_t)jrow * CIN + la_q * 4;
  const float* __restrict__ fW = Wall + (size_t)o * (CIN*COUT) + col0;

  float4 aP, wP[WLPT];
  aP = *(const float4*)&fA[0];
  #pragma unroll
  for (int i = 0; i < WLPT; ++i) {
    const int idx = tid + i*256, k = idx / NQ, q = idx - k*NQ;
    wP[i] = *(const float4*)&fW[(size_t)k * COUT + q*4];
  }

  float4 acc[MR];
  #pragma unroll
  for (int i = 0; i < MR; ++i) { acc[i].x=0.f; acc[i].y=0.f; acc[i].z=0.f; acc[i].w=0.f; }

  for (int t = 0; t < NT; ++t) {
    as[la_r][la_q*4+0] = aP.x;
    as[la_r][la_q*4+1] = aP.y;
    as[la_r][la_q*4+2] = aP.z;
    as[la_r][la_q*4+3] = aP.w;
    #pragma unroll
    for (int i = 0; i < WLPT; ++i) {
      const int idx = tid + i*256, k = idx / NQ, q = idx - k*NQ;
      *(float4*)&ws[k][q*4] = wP[i];
    }
    __syncthreads();
    if (t + 1 < NT) {
      const int k0 = (t + 1) * KT;
      aP = *(const float4*)&fA[k0];
      #pragma unroll
      for (int i = 0; i < WLPT; ++i) {
        const int idx = tid + i*256, k = idx / NQ, q = idx - k*NQ;
        wP[i] = *(const float4*)&fW[(size_t)(k0 + k) * COUT + q*4];
      }
    }
    #pragma unroll
    for (int k = 0; k < KT; ++k) {
      const float4 wv = *(const float4*)&ws[k][cq*4];
      #pragma unroll
      for (int i = 0; i < MR; ++i) {
        const float av = as[ty*MR + i][k];
        acc[i].x = fmaf(av, wv.x, acc[i].x);
        acc[i].y = fmaf(av, wv.y, acc[i].y);
        acc[i].z = fmaf(av, wv.z, acc[i].z);
        acc[i].w = fmaf(av, wv.w, acc[i].w);
      }
    }
    __syncthreads();
  }
  #pragma unroll
  for (int i = 0; i < MR; ++i) {
    const int p = row0 + ty*MR + i;
    const int slot = sbase + p;
    if (p < m && slot < SLOTCAP)
      *(float4*)&P[(size_t)slot * COUT + col0 + cq*4] = acc[i];
  }
}

// ---------------- phase 2: per-site deterministic sum of partials ----------------
template<int COUT>
__global__ __launch_bounds__(256) void k_psum(float* __restrict__ out,
    const float* __restrict__ P, const int* __restrict__ pslot,
    const int* __restrict__ obase, const int* __restrict__ cnt,
    const int* __restrict__ nactp)
{
  constexpr int SLOTCAP = (40*1024*1024) / (COUT*4);
  const int idx = blockIdx.x * 256 + threadIdx.x;
  const int i = idx / COUT;
  if (i >= *nactp) return;
  const int n = cnt[i];
  if (n == 0) return;
  const int cc = idx - i * COUT;
  float acc = 0.f;
  for (int h = 0; h < n; ++h) {
    const int e = pslot[i * MAXE + h];
    if (e < 0) continue;
    const int slot = obase[e >> 8] + (e & 0xFF);
    if (slot >= SLOTCAP) continue;
    acc += P[(size_t)slot * COUT + cc];
  }
  out[idx] += acc;
}

// ---------------- BN stats -> scale/shift ----------------
template<int COUT>
__global__ __launch_bounds__(256) void k_bnstats(const float* __restrict__ x,
    const float* __restrict__ g, const float* __restrict__ b,
    float* __restrict__ scale, float* __restrict__ shift, const int* __restrict__ nactp)
{
  const int c = blockIdx.x;
  const int tid = threadIdx.x;
  double s1 = 0.0, s2 = 0.0;
  for (int r = tid; r < NV; r += 256) {
    const double v = (double)x[r * COUT + c];
    s1 += v; s2 += v * v;
  }
  __shared__ double r1[256], r2[256];
  r1[tid] = s1; r2[tid] = s2;
  __syncthreads();
  for (int off = 128; off > 0; off >>= 1) {
    if (tid < off) { r1[tid] += r1[tid + off]; r2[tid] += r2[tid + off]; }
    __syncthreads();
  }
  if (tid == 0) {
    const double n = (double)(*nactp);
    const double mu = r1[0] / n;
    double var = r2[0] / n - mu * mu;
    if (var < 0.0) var = 0.0;
    const double sc = (double)g[c] / sqrt(var + 1e-4);
    scale[c] = (float)sc;
    shift[c] = (float)((double)b[c] - mu * sc);
  }
}

// ---------------- BN apply + ReLU (in place) ----------------
template<int COUT>
__global__ __launch_bounds__(256) void k_bnrelu(float* __restrict__ x,
    const float* __restrict__ scale, const float* __restrict__ shift,
    const int* __restrict__ nactp)
{
  const int idx = blockIdx.x * 256 + threadIdx.x;
  if (idx >= NV * COUT) return;
  const int i = idx / COUT, c = idx % COUT;
  float v = 0.f;
  if (i < *nactp) {
    const float y = fmaf(x[idx], scale[c], shift[c]);
    v = (y > 0.f) ? y : 0.f;
  }
  x[idx] = v;
}

// ---------------- pooling ----------------
__global__ __launch_bounds__(256) void k_poolkey(const int* __restrict__ c,
    long long* __restrict__ pk, const int* __restrict__ nactp,
    int sd, int sh, int sw, int oD, int oH, int oW)
{
  const int i = blockIdx.x * 256 + threadIdx.x;
  if (i >= NV) return;
  if (i < *nactp) {
    const int b = c[i*4+0];
    const int d = c[i*4+1] / sd, h = c[i*4+2] / sh, w = c[i*4+3] / sw;
    pk[i] = (((long long)b*oD + d)*oH + h)*(long long)oW + w;
  } else pk[i] = BIGK;
}

__global__ __launch_bounds__(1024) void k_sortcompact(const long long* __restrict__ pk,
    int* __restrict__ cNew, int* __restrict__ map, int* __restrict__ nactOut,
    int D, int H, int Wd)
{
  __shared__ long long sk[NV];
  __shared__ int si[NV];
  __shared__ int sc[NV];
  __shared__ int s2[NV];
  const int tid = threadIdx.x;
  for (int e = 0; e < 2; ++e) { const int t = tid + e*1024; sk[t] = pk[t]; si[t] = t; }
  __syncthreads();
  for (int k = 2; k <= NV; k <<= 1)
    for (int j = k >> 1; j > 0; j >>= 1) {
      for (int e = 0; e < 2; ++e) {
        const int i = tid + e*1024;
        const int ixj = i ^ j;
        if (ixj > i) {
          const bool up = ((i & k) == 0);
          const long long a = sk[i], bb = sk[ixj];
          const bool sw = up ? (a > bb) : (a < bb);
          if (sw) { sk[i] = bb; sk[ixj] = a; const int t2 = si[i]; si[i] = si[ixj]; si[ixj] = t2; }
        }
      }
      __syncthreads();
    }
  for (int e = 0; e < 2; ++e) {
    const int t = tid + e*1024;
    sc[t] = (sk[t] != BIGK && (t == 0 || sk[t] != sk[t-1])) ? 1 : 0;
  }
  __syncthreads();
  for (int d2 = 1; d2 < NV; d2 <<= 1) {
    for (int e = 0; e < 2; ++e) { const int t = tid + e*1024; s2[t] = sc[t] + ((t >= d2) ? sc[t - d2] : 0); }
    __syncthreads();
    for (int e = 0; e < 2; ++e) { const int t = tid + e*1024; sc[t] = s2[t]; }
    __syncthreads();
  }
  for (int e = 0; e < 2; ++e) {
    const int t = tid + e*1024;
    const long long key = sk[t];
    if (key != BIGK) {
      const int g = sc[t] - 1;
      map[si[t]] = g;
      if (t == 0 || sk[t-1] != key) {
        const int w = (int)(key % Wd);
        long long r = key / Wd;
        const int h = (int)(r % H); r /= H;
        const int d = (int)(r % D);
        const int b = (int)(r / D);
        cNew[g*4+0] = b; cNew[g*4+1] = d; cNew[g*4+2] = h; cNew[g*4+3] = w;
      }
    }
  }
  if (tid == 0) *nactOut = sc[NV-1];
}

__global__ __launch_bounds__(256) void k_zero(float* __restrict__ x, int n) {
  const int idx = blockIdx.x * 256 + threadIdx.x;
  if (idx < n) x[idx] = 0.f;
}

template<int C>
__global__ __launch_bounds__(256) void k_pscatter(const float* __restrict__ src,
    float* __restrict__ dst, const int* __restrict__ map, const int* __restrict__ nactp)
{
  const int idx = blockIdx.x * 256 + threadIdx.x;
  const int i = idx / C;
  if (i >= *nactp) return;
  atomicMax((unsigned*)&dst[map[i] * C + (idx % C)], __float_as_uint(src[idx]));
}

// ---------------- final dense scatter ----------------
__global__ __launch_bounds__(256) void k_out(const float* __restrict__ f,
    const int* __restrict__ c, float* __restrict__ out, const int* __restrict__ nactp)
{
  const int idx = blockIdx.x * 256 + threadIdx.x;
  const int i = idx >> 9, ch = idx & 511;
  if (i >= *nactp) return;
  const int b = c[i*4+0], d = c[i*4+1], h = c[i*4+2], w = c[i*4+3];
  out[ (((b*512 + ch)*2 + d)*111 + h)*98 + w ] = f[idx];
}

// ---------------- host orchestration ----------------
template<int K, int CIN, int C>
static void run_stage(hipStream_t stream, int s,
    const float* Wa, const float* Ga, const float* Ba,
    const float* Wb, const float* Gb, const float* Bb,
    float* fX, float* fY, int* cX, int* cY,
    int D, int H, int W, int pd, int ph, int pw, int oD, int oH, int oW,
    long long* hk, int* hv, long long* pkey, int* pslot, int* cnt, int* map,
    int* nact, float* scale, float* shift,
    int* ocnt, int* obase, int* olist, float* P)
{
  constexpr int K3 = K*K*K;
  constexpr int CTR = K3/2;
  constexpr int BN   = (C < 128) ? C : 128;
  constexpr int NCB  = C / BN;
  constexpr int NRT  = MAXP / 32;
  constexpr int GEMM_G = (NV / 32) * NCB;
  constexpr int POG_G  = K3 * NRT * NCB;
  const int* na = nact + s;
  k_hclear<<<HSIZE/256, 256, 0, stream>>>(hk, ocnt);
  k_hinsert<<<NV/256, 256, 0, stream>>>(cX, hk, hv, na, D, H, W);
  k_hits<K><<<NV/4, 256, 0, stream>>>(cX, hk, hv, na, pslot, cnt, ocnt, olist, D, H, W);
  k_oscan<<<1, 512, 0, stream>>>(ocnt, obase);

  if constexpr (CIN == 1) {
    k_gemm1<C><<<NV*C/256, 256, 0, stream>>>(fX, Wa + (size_t)CTR*CIN*C, fY);
    k_pgemm<1, C><<<K3, 256, 0, stream>>>(fX, Wa, P, ocnt, obase, olist);
  } else {
    k_gemm<CIN, C><<<GEMM_G, 256, 0, stream>>>(fX, Wa + (size_t)CTR*CIN*C, fY);
    k_pogemm<CIN, C><<<K3*NRT*NCB, 256, 0, stream>>>(fX, Wa, P, ocnt, obase, olist);
  }
  k_psum<C><<<NV*C/256, 256, 0, stream>>>(fY, P, pslot, obase, cnt, na);
  k_bnstats<C><<<C, 256, 0, stream>>>(fY, Ga, Ba, scale, shift, na);
  k_bnrelu<C><<<NV*C/256, 256, 0, stream>>>(fY, scale, shift, na);

  k_gemm<C, C><<<GEMM_G, 256, 0, stream>>>(fY, Wb + (size_t)CTR*C*C, fX);
  k_pogemm<C, C><<<POG_G, 256, 0, stream>>>(fY, Wb, P, ocnt, obase, olist);
  k_psum<C><<<NV*C/256, 256, 0, stream>>>(fX, P, pslot, obase, cnt, na);
  k_bnstats<C><<<C, 256, 0, stream>>>(fX, Gb, Bb, scale, shift, na);
  k_bnrelu<C><<<NV*C/256, 256, 0, stream>>>(fX, scale, shift, na);

  k_poolkey<<<NV/256, 256, 0, stream>>>(cX, pkey, na, pd, ph, pw, oD, oH, oW);
  k_sortcompact<<<1, 1024, 0, stream>>>(pkey, cY, map, nact + s + 1, oD, oH, oW);
  k_zero<<<NV*C/256, 256, 0, stream>>>(fY, NV*C);
  k_pscatter<C><<<NV*C/256, 256, 0, stream>>>(fX, fY, map, na);
}

extern "C" void kernel_launch(void* const* d_in, const int* in_sizes, int n_in,
                              void* d_out, int out_size, void* d_ws, size_t ws_size,
                              hipStream_t stream)
{
  const float* vf    = (const float*)d_in[0];
  const int*   coors = (const int*)d_in[1];
  const float *Wl[10], *Gl[10], *Bl[10];
  for (int i = 0; i < 10; ++i) {
    Wl[i] = (const float*)d_in[3 + 3*i];
    Gl[i] = (const float*)d_in[4 + 3*i];
    Bl[i] = (const float*)d_in[5 + 3*i];
  }

  char* p = (char*)d_ws;
  auto alloc = [&](size_t bytes) { char* q = p; p += (bytes + 255) & ~(size_t)255; return q; };
  float*     fB    = (float*)    alloc((size_t)NV*512*4);
  long long* hk    = (long long*)alloc((size_t)HSIZE*8);
  long long* pkey  = (long long*)alloc((size_t)NV*8);
  int*       hv    = (int*)      alloc((size_t)HSIZE*4);
  int*       cA    = (int*)      alloc((size_t)NV*4*4);
  int*       cB    = (int*)      alloc((size_t)NV*4*4);
  int*       pslot = (int*)      alloc((size_t)NV*MAXE*4);
  int*       cnt   = (int*)      alloc((size_t)NV*4);
  int*       map   = (int*)      alloc((size_t)NV*4);
  int*       nact  = (int*)      alloc(8*4);
  float*     scale = (float*)    alloc(512*4);
  float*     shift = (float*)    alloc(512*4);
  int*       ocnt  = (int*)      alloc((size_t)K3MAX*4);
  int*       obase = (int*)      alloc((size_t)K3MAX*4);

  // scratch aliased into d_out (89 MB); all dead before the final memset
  float* fA    = (float*)d_out;                                   // 4 MB
  float* P     = (float*)((char*)d_out + (size_t)8*1024*1024);    // 40 MB budget (SLOTCAP-guarded)
  int*   olist = (int*)  ((char*)d_out + (size_t)48*1024*1024);   // 343*256*4 = 351 KB

  k_init<<<NV/256, 256, 0, stream>>>(vf, coors, cA, fA, nact);

  run_stage<7, 1, 64>  (stream, 0, Wl[0],Gl[0],Bl[0], Wl[1],Gl[1],Bl[1],
    fA, fB, cA, cB, 216, 7992, 7056, 3, 3, 3, 72, 2664, 2352,
    hk, hv, pkey, pslot, cnt, map, nact, scale, shift, ocnt, obase, olist, P);
  run_stage<7, 64, 128>(stream, 1, Wl[2],Gl[2],Bl[2], Wl[3],Gl[3],Bl[3],
    fB, fA, cB, cA, 72, 2664, 2352, 3, 3, 3, 24, 888, 784,
    hk, hv, pkey, pslot, cnt, map, nact, scale, shift, ocnt, obase, olist, P);
  run_stage<5, 128, 256>(stream, 2, Wl[4],Gl[4],Bl[4], Wl[5],Gl[5],Bl[5],
    fA, fB, cA, cB, 24, 888, 784, 3, 2, 2, 8, 444, 392,
    hk, hv, pkey, pslot, cnt, map, nact, scale, shift, ocnt, obase, olist, P);
  run_stage<3, 256, 384>(stream, 3, Wl[6],Gl[6],Bl[6], Wl[7],Gl[7],Bl[7],
    fB, fA, cB, cA, 8, 444, 392, 2, 2, 2, 4, 222, 196,
    hk, hv, pkey, pslot, cnt, map, nact, scale, shift, ocnt, obase, olist, P);
  run_stage<3, 384, 512>(stream, 4, Wl[8],Gl[8],Bl[8], Wl[9],Gl[9],Bl[9],
    fA, fB, cA, cB, 4, 222, 196, 2, 2, 2, 2, 111, 98,
    hk, hv, pkey, pslot, cnt, map, nact, scale, shift, ocnt, obase, olist, P);

  hipMemsetAsync(d_out, 0, (size_t)out_size * sizeof(float), stream);
  k_out<<<NV*512/256, 256, 0, stream>>>(fB, cB, (float*)d_out, nact + 5);
}

// Round 8
// 813.474 us; speedup vs baseline: 1.1446x; 1.1446x over previous
//
#include <hip/hip_runtime.h>
#include <climits>
#include <cstdint>

#define NV    2048
#define MAXE  344
#define HSIZE 8192
#define HMASK 8191
#define BIGK  LLONG_MAX
#define K3MAX 343
#define MAXP  256
#define PBUDGET (76ull*1024*1024)

__device__ __forceinline__ unsigned hashk(long long k) {
  unsigned long long x = (unsigned long long)k * 0x9E3779B97F4A7C15ull;
  return (unsigned)(x >> 51) & HMASK;
}

// ---------------- init ----------------
__global__ __launch_bounds__(256) void k_init(const float* __restrict__ vf,
    const int* __restrict__ coors, int* __restrict__ cA, float* __restrict__ fA,
    int* __restrict__ nact)
{
  int i = blockIdx.x * 256 + threadIdx.x;
  if (i == 0) nact[0] = NV;
  if (i >= NV) return;
  cA[i*4+0] = coors[i*4+0];
  cA[i*4+1] = coors[i*4+1];
  cA[i*4+2] = coors[i*4+2];
  cA[i*4+3] = coors[i*4+3];
  fA[i] = vf[i];
}

// ---------------- hash ----------------
__global__ __launch_bounds__(256) void k_hclear(long long* __restrict__ hk,
    int* __restrict__ ocnt)
{
  int i = blockIdx.x * 256 + threadIdx.x;
  if (i < HSIZE) hk[i] = -1LL;
  if (i < K3MAX) ocnt[i] = 0;
}

__global__ __launch_bounds__(256) void k_hinsert(const int* __restrict__ c,
    long long* __restrict__ hk, int* __restrict__ hv, const int* __restrict__ nactp,
    int D, int H, int Wd)
{
  int i = blockIdx.x * 256 + threadIdx.x;
  if (i >= NV || i >= *nactp) return;
  long long key = (((long long)c[i*4+0]*D + c[i*4+1])*H + c[i*4+2])*(long long)Wd + c[i*4+3];
  unsigned h = hashk(key);
  while (true) {
    unsigned long long old = atomicCAS((unsigned long long*)&hk[h], ~0ull, (unsigned long long)key);
    if (old == ~0ull) { hv[h] = i; break; }
    h = (h + 1) & HMASK;
  }
}

// ---------------- neighbor hit lists (one wave per site), grouped by offset ----------------
template<int K>
__global__ __launch_bounds__(256) void k_hits(const int* __restrict__ c,
    const long long* __restrict__ hk, const int* __restrict__ hv,
    const int* __restrict__ nactp, int* __restrict__ pslot, int* __restrict__ cnt,
    int* __restrict__ ocnt, int* __restrict__ olist,
    int D, int H, int Wd)
{
  constexpr int K3 = K*K*K, R = K/2, CTR = K3/2;
  const int site = blockIdx.x * 4 + (threadIdx.x >> 6);
  const int lane = threadIdx.x & 63;
  const int nact = *nactp;
  if (site >= NV) return;
  if (site >= nact) { if (lane == 0) cnt[site] = 0; return; }
  const int b = c[site*4+0], d = c[site*4+1], hc = c[site*4+2], w = c[site*4+3];
  int base = 0;
  for (int o0 = 0; o0 < K3; o0 += 64) {
    const int o = o0 + lane;
    int j = -1;
    if (o < K3 && o != CTR) {
      const int dz = o/(K*K) - R, dy = (o/K)%K - R, dx = o%K - R;
      const int nd = d+dz, nh = hc+dy, nw = w+dx;
      if (nd >= 0 && nd < D && nh >= 0 && nh < H && nw >= 0 && nw < Wd) {
        const long long key = (((long long)b*D + nd)*H + nh)*(long long)Wd + nw;
        unsigned hs = hashk(key);
        while (true) {
          const long long kk = hk[hs];
          if (kk == -1LL) break;
          if (kk == key) { j = hv[hs]; break; }
          hs = (hs + 1) & HMASK;
        }
      }
    }
    const unsigned long long m = __ballot(j >= 0);
    if (j >= 0) {
      const int pos = __popcll(m & ((1ull << lane) - 1ull));
      const int p = atomicAdd(&ocnt[o], 1);
      int tag = -1;
      if (p < MAXP) { olist[o * MAXP + p] = (site << 12) | j; tag = (o << 8) | p; }
      pslot[site * MAXE + base + pos] = tag;
    }
    base += __popcll(m);
  }
  if (lane == 0) cnt[site] = base;
}

// ---------------- exclusive scan of per-offset hit counts -> compact slot bases ----------------
__global__ __launch_bounds__(512) void k_oscan(const int* __restrict__ ocnt,
    int* __restrict__ obase)
{
  __shared__ int s[512];
  const int t = threadIdx.x;
  const int v = (t < K3MAX) ? min(ocnt[t], MAXP) : 0;
  s[t] = v;
  __syncthreads();
  for (int d = 1; d < 512; d <<= 1) {
    const int x = (t >= d) ? s[t - d] : 0;
    __syncthreads();
    s[t] += x;
    __syncthreads();
  }
  if (t < K3MAX) obase[t] = s[t] - v;
}

// ---------------- center GEMM, CIN==1: outer product ----------------
template<int COUT>
__global__ __launch_bounds__(256) void k_gemm1(const float* __restrict__ f,
    const float* __restrict__ Wc, float* __restrict__ out)
{
  const int idx = blockIdx.x * 256 + threadIdx.x;
  if (idx >= NV * COUT) return;
  const int i = idx / COUT, c = idx - i * COUT;
  out[idx] = f[i] * Wc[c];
}

// ---------------- dense center GEMM: LDS-tiled, reg-prefetch double buffer ----------------
template<int CIN, int COUT>
__global__ __launch_bounds__(256) void k_gemm(const float* __restrict__ f,
    const float* __restrict__ Wc, float* __restrict__ out)
{
  constexpr int BN = (COUT < 128) ? COUT : 128;
  constexpr int NQ = BN / 4;
  constexpr int TY = 256 / NQ;
  constexpr int BM = 32;
  constexpr int MR = BM / TY;
  constexpr int KT = 32;
  constexpr int NT = CIN / KT;
  constexpr int NCB = COUT / BN;
  constexpr int WLPT = (KT * NQ) / 256;
  __shared__ float as[BM][KT + 1];
  __shared__ float ws[KT][BN];

  const int rb = blockIdx.x / NCB;
  const int cb = blockIdx.x - rb * NCB;
  const int row0 = rb * BM;
  const int col0 = cb * BN;
  const int tid = threadIdx.x;
  const int cq = tid % NQ;
  const int ty = tid / NQ;
  const int la_r = tid >> 3;
  const int la_q = tid & 7;

  const float* __restrict__ fA = f + (size_t)(row0 + la_r) * CIN + la_q * 4;
  const float* __restrict__ fW = Wc + col0;

  float4 aP, wP[WLPT];
  aP = *(const float4*)&fA[0];
  #pragma unroll
  for (int i = 0; i < WLPT; ++i) {
    const int idx = tid + i*256, k = idx / NQ, q = idx - k*NQ;
    wP[i] = *(const float4*)&fW[(size_t)k * COUT + q*4];
  }

  float4 acc[MR];
  #pragma unroll
  for (int i = 0; i < MR; ++i) { acc[i].x=0.f; acc[i].y=0.f; acc[i].z=0.f; acc[i].w=0.f; }

  for (int t = 0; t < NT; ++t) {
    as[la_r][la_q*4+0] = aP.x;
    as[la_r][la_q*4+1] = aP.y;
    as[la_r][la_q*4+2] = aP.z;
    as[la_r][la_q*4+3] = aP.w;
    #pragma unroll
    for (int i = 0; i < WLPT; ++i) {
      const int idx = tid + i*256, k = idx / NQ, q = idx - k*NQ;
      *(float4*)&ws[k][q*4] = wP[i];
    }
    __syncthreads();
    if (t + 1 < NT) {
      const int k0 = (t + 1) * KT;
      aP = *(const float4*)&fA[k0];
      #pragma unroll
      for (int i = 0; i < WLPT; ++i) {
        const int idx = tid + i*256, k = idx / NQ, q = idx - k*NQ;
        wP[i] = *(const float4*)&fW[(size_t)(k0 + k) * COUT + q*4];
      }
    }
    #pragma unroll
    for (int k = 0; k < KT; ++k) {
      const float4 wv = *(const float4*)&ws[k][cq*4];
      #pragma unroll
      for (int i = 0; i < MR; ++i) {
        const float av = as[ty*MR + i][k];
        acc[i].x = fmaf(av, wv.x, acc[i].x);
        acc[i].y = fmaf(av, wv.y, acc[i].y);
        acc[i].z = fmaf(av, wv.z, acc[i].z);
        acc[i].w = fmaf(av, wv.w, acc[i].w);
      }
    }
    __syncthreads();
  }
  #pragma unroll
  for (int i = 0; i < MR; ++i)
    *(float4*)&out[(size_t)(row0 + ty*MR + i) * COUT + col0 + cq*4] = acc[i];
}

// ---------------- legacy pgemm: used only for CIN==1 (layer 0), tiny ----------------
template<int CIN, int COUT>
__global__ __launch_bounds__(256) void k_pgemm(const float* __restrict__ f,
    const float* __restrict__ Wall, float* __restrict__ P,
    const int* __restrict__ ocnt, const int* __restrict__ obase,
    const int* __restrict__ olist)
{
  constexpr int SLOTCAP = (int)(PBUDGET / (COUT*4));
  const int o = blockIdx.x;
  int m = ocnt[o];
  if (m == 0) return;
  if (m > MAXP) m = MAXP;
  const int sbase = obase[o];
  const int tid = threadIdx.x;
  const float* __restrict__ Wo = Wall + (size_t)o * (CIN*COUT);
  for (int p = 0; p < m; ++p) {
    const int j = olist[o*MAXP + p] & 0xFFF;
    const float fv = f[j];   // CIN == 1
    const int slot = sbase + p;
    if (slot < SLOTCAP && tid < COUT)
      P[(size_t)slot*COUT + tid] = fv * Wo[tid];
  }
}

// ---------------- per-(offset, k-chunk) gather-GEMM ----------------
// P[(slot*KSP+ksp)*COUT + c] = sum_{k in chunk ksp} f[j_slot][k] * W[o][k][c]
template<int CIN, int COUT, int KSP>
__global__ __launch_bounds__(256) void k_pogemm(const float* __restrict__ f,
    const float* __restrict__ Wall, float* __restrict__ P,
    const int* __restrict__ ocnt, const int* __restrict__ obase,
    const int* __restrict__ olist)
{
  constexpr int KCH = CIN / KSP;               // <=128, multiple of 32
  constexpr int BN = (COUT < 128) ? COUT : 128;
  constexpr int NQ = BN / 4;
  constexpr int TY = 256 / NQ;
  constexpr int BM = 32;
  constexpr int MR = BM / TY;
  constexpr int KT = 32;
  constexpr int NT = KCH / KT;
  constexpr int NCB = COUT / BN;
  constexpr int NRT = MAXP / BM;
  constexpr int WLPT = (KT * NQ) / 256;
  constexpr int SLOTCAP = (int)(PBUDGET / ((size_t)KSP*COUT*4));
  __shared__ float as[BM][KT + 1];
  __shared__ float ws[KT][BN];

  const int o    = blockIdx.x / (NRT * NCB * KSP);
  int rem        = blockIdx.x - o * (NRT * NCB * KSP);
  const int rt   = rem / (NCB * KSP);
  rem           -= rt * (NCB * KSP);
  const int cb   = rem / KSP;
  const int ksp  = rem - cb * KSP;
  int m = ocnt[o];
  if (m > MAXP) m = MAXP;
  const int row0 = rt * BM;
  if (m == 0 || row0 >= m) return;
  const int sbase = obase[o];
  const int col0 = cb * BN;
  const int kch0 = ksp * KCH;
  const int tid = threadIdx.x;
  const int cq = tid % NQ;
  const int ty = tid / NQ;
  const int la_r = tid >> 3;
  const int la_q = tid & 7;

  const int pA = row0 + la_r;
  const int jrow = olist[o*MAXP + ((pA < m) ? pA : row0)] & 0xFFF;
  const float* __restrict__ fA = f + (size_t)jrow * CIN + kch0 + la_q * 4;
  const float* __restrict__ fW = Wall + (size_t)o * (CIN*COUT) + (size_t)kch0 * COUT + col0;

  float4 aP, wP[WLPT];
  aP = *(const float4*)&fA[0];
  #pragma unroll
  for (int i = 0; i < WLPT; ++i) {
    const int idx = tid + i*256, k = idx / NQ, q = idx - k*NQ;
    wP[i] = *(const float4*)&fW[(size_t)k * COUT + q*4];
  }

  float4 acc[MR];
  #pragma unroll
  for (int i = 0; i < MR; ++i) { acc[i].x=0.f; acc[i].y=0.f; acc[i].z=0.f; acc[i].w=0.f; }

  for (int t = 0; t < NT; ++t) {
    as[la_r][la_q*4+0] = aP.x;
    as[la_r][la_q*4+1] = aP.y;
    as[la_r][la_q*4+2] = aP.z;
    as[la_r][la_q*4+3] = aP.w;
    #pragma unroll
    for (int i = 0; i < WLPT; ++i) {
      const int idx = tid + i*256, k = idx / NQ, q = idx - k*NQ;
      *(float4*)&ws[k][q*4] = wP[i];
    }
    __syncthreads();
    if (t + 1 < NT) {
      const int k0 = (t + 1) * KT;
      aP = *(const float4*)&fA[k0];
      #pragma unroll
      for (int i = 0; i < WLPT; ++i) {
        const int idx = tid + i*256, k = idx / NQ, q = idx - k*NQ;
        wP[i] = *(const float4*)&fW[(size_t)(k0 + k) * COUT + q*4];
      }
    }
    #pragma unroll
    for (int k = 0; k < KT; ++k) {
      const float4 wv = *(const float4*)&ws[k][cq*4];
      #pragma unroll
      for (int i = 0; i < MR; ++i) {
        const float av = as[ty*MR + i][k];
        acc[i].x = fmaf(av, wv.x, acc[i].x);
        acc[i].y = fmaf(av, wv.y, acc[i].y);
        acc[i].z = fmaf(av, wv.z, acc[i].z);
        acc[i].w = fmaf(av, wv.w, acc[i].w);
      }
    }
    __syncthreads();
  }
  #pragma unroll
  for (int i = 0; i < MR; ++i) {
    const int p = row0 + ty*MR + i;
    const int slot = sbase + p;
    if (p < m && slot < SLOTCAP)
      *(float4*)&P[((size_t)slot * KSP + ksp) * COUT + col0 + cq*4] = acc[i];
  }
}

// ---------------- phase 2: per-site deterministic sum of partials ----------------
template<int COUT, int KSP>
__global__ __launch_bounds__(256) void k_psum(float* __restrict__ out,
    const float* __restrict__ P, const int* __restrict__ pslot,
    const int* __restrict__ obase, const int* __restrict__ cnt,
    const int* __restrict__ nactp)
{
  constexpr int SLOTCAP = (int)(PBUDGET / ((size_t)KSP*COUT*4));
  const int idx = blockIdx.x * 256 + threadIdx.x;
  const int i = idx / COUT;
  if (i >= *nactp) return;
  const int n = cnt[i];
  if (n == 0) return;
  const int cc = idx - i * COUT;
  float acc = 0.f;
  for (int h = 0; h < n; ++h) {
    const int e = pslot[i * MAXE + h];
    if (e < 0) continue;
    const int slot = obase[e >> 8] + (e & 0xFF);
    if (slot >= SLOTCAP) continue;
    #pragma unroll
    for (int ksp = 0; ksp < KSP; ++ksp)
      acc += P[((size_t)slot * KSP + ksp) * COUT + cc];
  }
  out[idx] += acc;
}

// ---------------- BN stats -> scale/shift ----------------
template<int COUT>
__global__ __launch_bounds__(256) void k_bnstats(const float* __restrict__ x,
    const float* __restrict__ g, const float* __restrict__ b,
    float* __restrict__ scale, float* __restrict__ shift, const int* __restrict__ nactp)
{
  const int c = blockIdx.x;
  const int tid = threadIdx.x;
  double s1 = 0.0, s2 = 0.0;
  for (int r = tid; r < NV; r += 256) {
    const double v = (double)x[r * COUT + c];
    s1 += v; s2 += v * v;
  }
  __shared__ double r1[256], r2[256];
  r1[tid] = s1; r2[tid] = s2;
  __syncthreads();
  for (int off = 128; off > 0; off >>= 1) {
    if (tid < off) { r1[tid] += r1[tid + off]; r2[tid] += r2[tid + off]; }
    __syncthreads();
  }
  if (tid == 0) {
    const double n = (double)(*nactp);
    const double mu = r1[0] / n;
    double var = r2[0] / n - mu * mu;
    if (var < 0.0) var = 0.0;
    const double sc = (double)g[c] / sqrt(var + 1e-4);
    scale[c] = (float)sc;
    shift[c] = (float)((double)b[c] - mu * sc);
  }
}

// ---------------- BN apply + ReLU (in place) ----------------
template<int COUT>
__global__ __launch_bounds__(256) void k_bnrelu(float* __restrict__ x,
    const float* __restrict__ scale, const float* __restrict__ shift,
    const int* __restrict__ nactp)
{
  const int idx = blockIdx.x * 256 + threadIdx.x;
  if (idx >= NV * COUT) return;
  const int i = idx / COUT, c = idx % COUT;
  float v = 0.f;
  if (i < *nactp) {
    const float y = fmaf(x[idx], scale[c], shift[c]);
    v = (y > 0.f) ? y : 0.f;
  }
  x[idx] = v;
}

// ---------------- pooling ----------------
__global__ __launch_bounds__(256) void k_poolkey(const int* __restrict__ c,
    long long* __restrict__ pk, const int* __restrict__ nactp,
    int sd, int sh, int sw, int oD, int oH, int oW)
{
  const int i = blockIdx.x * 256 + threadIdx.x;
  if (i >= NV) return;
  if (i < *nactp) {
    const int b = c[i*4+0];
    const int d = c[i*4+1] / sd, h = c[i*4+2] / sh, w = c[i*4+3] / sw;
    pk[i] = (((long long)b*oD + d)*oH + h)*(long long)oW + w;
  } else pk[i] = BIGK;
}

__global__ __launch_bounds__(1024) void k_sortcompact(const long long* __restrict__ pk,
    int* __restrict__ cNew, int* __restrict__ map, int* __restrict__ nactOut,
    int D, int H, int Wd)
{
  __shared__ long long sk[NV];
  __shared__ int si[NV];
  __shared__ int sc[NV];
  __shared__ int s2[NV];
  const int tid = threadIdx.x;
  for (int e = 0; e < 2; ++e) { const int t = tid + e*1024; sk[t] = pk[t]; si[t] = t; }
  __syncthreads();
  for (int k = 2; k <= NV; k <<= 1)
    for (int j = k >> 1; j > 0; j >>= 1) {
      for (int e = 0; e < 2; ++e) {
        const int i = tid + e*1024;
        const int ixj = i ^ j;
        if (ixj > i) {
          const bool up = ((i & k) == 0);
          const long long a = sk[i], bb = sk[ixj];
          const bool sw = up ? (a > bb) : (a < bb);
          if (sw) { sk[i] = bb; sk[ixj] = a; const int t2 = si[i]; si[i] = si[ixj]; si[ixj] = t2; }
        }
      }
      __syncthreads();
    }
  for (int e = 0; e < 2; ++e) {
    const int t = tid + e*1024;
    sc[t] = (sk[t] != BIGK && (t == 0 || sk[t] != sk[t-1])) ? 1 : 0;
  }
  __syncthreads();
  for (int d2 = 1; d2 < NV; d2 <<= 1) {
    for (int e = 0; e < 2; ++e) { const int t = tid + e*1024; s2[t] = sc[t] + ((t >= d2) ? sc[t - d2] : 0); }
    __syncthreads();
    for (int e = 0; e < 2; ++e) { const int t = tid + e*1024; sc[t] = s2[t]; }
    __syncthreads();
  }
  for (int e = 0; e < 2; ++e) {
    const int t = tid + e*1024;
    const long long key = sk[t];
    if (key != BIGK) {
      const int g = sc[t] - 1;
      map[si[t]] = g;
      if (t == 0 || sk[t-1] != key) {
        const int w = (int)(key % Wd);
        long long r = key / Wd;
        const int h = (int)(r % H); r /= H;
        const int d = (int)(r % D);
        const int b = (int)(r / D);
        cNew[g*4+0] = b; cNew[g*4+1] = d; cNew[g*4+2] = h; cNew[g*4+3] = w;
      }
    }
  }
  if (tid == 0) *nactOut = sc[NV-1];
}

__global__ __launch_bounds__(256) void k_zero(float* __restrict__ x, int n) {
  const int idx = blockIdx.x * 256 + threadIdx.x;
  if (idx < n) x[idx] = 0.f;
}

template<int C>
__global__ __launch_bounds__(256) void k_pscatter(const float* __restrict__ src,
    float* __restrict__ dst, const int* __restrict__ map, const int* __restrict__ nactp)
{
  const int idx = blockIdx.x * 256 + threadIdx.x;
  const int i = idx / C;
  if (i >= *nactp) return;
  atomicMax((unsigned*)&dst[map[i] * C + (idx % C)], __float_as_uint(src[idx]));
}

// ---------------- final dense scatter ----------------
__global__ __launch_bounds__(256) void k_out(const float* __restrict__ f,
    const int* __restrict__ c, float* __restrict__ out, const int* __restrict__ nactp)
{
  const int idx = blockIdx.x * 256 + threadIdx.x;
  const int i = idx >> 9, ch = idx & 511;
  if (i >= *nactp) return;
  const int b = c[i*4+0], d = c[i*4+1], h = c[i*4+2], w = c[i*4+3];
  out[ (((b*512 + ch)*2 + d)*111 + h)*98 + w ] = f[idx];
}

// ---------------- host orchestration ----------------
template<int K, int CIN, int C>
static void run_stage(hipStream_t stream, int s,
    const float* Wa, const float* Ga, const float* Ba,
    const float* Wb, const float* Gb, const float* Bb,
    float* fX, float* fY, int* cX, int* cY,
    int D, int H, int W, int pd, int ph, int pw, int oD, int oH, int oW,
    long long* hk, int* hv, long long* pkey, int* pslot, int* cnt, int* map,
    int* nact, float* scale, float* shift,
    int* ocnt, int* obase, int* olist, float* P)
{
  constexpr int K3 = K*K*K;
  constexpr int CTR = K3/2;
  constexpr int BN   = (C < 128) ? C : 128;
  constexpr int NCB  = C / BN;
  constexpr int NRT  = MAXP / 32;
  constexpr int GEMM_G = (NV / 32) * NCB;
  constexpr int KSPa = (CIN + 127) / 128;   // 1,1,2,3,4 for CIN=64..512
  constexpr int KSPb = (C + 127) / 128;
  const int* na = nact + s;
  k_hclear<<<HSIZE/256, 256, 0, stream>>>(hk, ocnt);
  k_hinsert<<<NV/256, 256, 0, stream>>>(cX, hk, hv, na, D, H, W);
  k_hits<K><<<NV/4, 256, 0, stream>>>(cX, hk, hv, na, pslot, cnt, ocnt, olist, D, H, W);
  k_oscan<<<1, 512, 0, stream>>>(ocnt, obase);

  if constexpr (CIN == 1) {
    k_gemm1<C><<<NV*C/256, 256, 0, stream>>>(fX, Wa + (size_t)CTR*CIN*C, fY);
    k_pgemm<1, C><<<K3, 256, 0, stream>>>(fX, Wa, P, ocnt, obase, olist);
    k_psum<C, 1><<<NV*C/256, 256, 0, stream>>>(fY, P, pslot, obase, cnt, na);
  } else {
    k_gemm<CIN, C><<<GEMM_G, 256, 0, stream>>>(fX, Wa + (size_t)CTR*CIN*C, fY);
    k_pogemm<CIN, C, KSPa><<<K3*NRT*NCB*KSPa, 256, 0, stream>>>(fX, Wa, P, ocnt, obase, olist);
    k_psum<C, KSPa><<<NV*C/256, 256, 0, stream>>>(fY, P, pslot, obase, cnt, na);
  }
  k_bnstats<C><<<C, 256, 0, stream>>>(fY, Ga, Ba, scale, shift, na);
  k_bnrelu<C><<<NV*C/256, 256, 0, stream>>>(fY, scale, shift, na);

  k_gemm<C, C><<<GEMM_G, 256, 0, stream>>>(fY, Wb + (size_t)CTR*C*C, fX);
  k_pogemm<C, C, KSPb><<<K3*NRT*NCB*KSPb, 256, 0, stream>>>(fY, Wb, P, ocnt, obase, olist);
  k_psum<C, KSPb><<<NV*C/256, 256, 0, stream>>>(fX, P, pslot, obase, cnt, na);
  k_bnstats<C><<<C, 256, 0, stream>>>(fX, Gb, Bb, scale, shift, na);
  k_bnrelu<C><<<NV*C/256, 256, 0, stream>>>(fX, scale, shift, na);

  k_poolkey<<<NV/256, 256, 0, stream>>>(cX, pkey, na, pd, ph, pw, oD, oH, oW);
  k_sortcompact<<<1, 1024, 0, stream>>>(pkey, cY, map, nact + s + 1, oD, oH, oW);
  k_zero<<<NV*C/256, 256, 0, stream>>>(fY, NV*C);
  k_pscatter<C><<<NV*C/256, 256, 0, stream>>>(fX, fY, map, na);
}

extern "C" void kernel_launch(void* const* d_in, const int* in_sizes, int n_in,
                              void* d_out, int out_size, void* d_ws, size_t ws_size,
                              hipStream_t stream)
{
  const float* vf    = (const float*)d_in[0];
  const int*   coors = (const int*)d_in[1];
  const float *Wl[10], *Gl[10], *Bl[10];
  for (int i = 0; i < 10; ++i) {
    Wl[i] = (const float*)d_in[3 + 3*i];
    Gl[i] = (const float*)d_in[4 + 3*i];
    Bl[i] = (const float*)d_in[5 + 3*i];
  }

  char* p = (char*)d_ws;
  auto alloc = [&](size_t bytes) { char* q = p; p += (bytes + 255) & ~(size_t)255; return q; };
  float*     fB    = (float*)    alloc((size_t)NV*512*4);
  long long* hk    = (long long*)alloc((size_t)HSIZE*8);
  long long* pkey  = (long long*)alloc((size_t)NV*8);
  int*       hv    = (int*)      alloc((size_t)HSIZE*4);
  int*       cA    = (int*)      alloc((size_t)NV*4*4);
  int*       cB    = (int*)      alloc((size_t)NV*4*4);
  int*       pslot = (int*)      alloc((size_t)NV*MAXE*4);
  int*       cnt   = (int*)      alloc((size_t)NV*4);
  int*       map   = (int*)      alloc((size_t)NV*4);
  int*       nact  = (int*)      alloc(8*4);
  float*     scale = (float*)    alloc(512*4);
  float*     shift = (float*)    alloc(512*4);
  int*       ocnt  = (int*)      alloc((size_t)K3MAX*4);
  int*       obase = (int*)      alloc((size_t)K3MAX*4);

  // scratch aliased into d_out (89 MB); all dead before the final memset
  float* fA    = (float*)d_out;                                   // 4 MB
  int*   olist = (int*)  ((char*)d_out + (size_t)8*1024*1024);    // 343*256*4 = 351 KB
  float* P     = (float*)((char*)d_out + (size_t)9*1024*1024);    // 76 MB budget (SLOTCAP-guarded)

  k_init<<<NV/256, 256, 0, stream>>>(vf, coors, cA, fA, nact);

  run_stage<7, 1, 64>  (stream, 0, Wl[0],Gl[0],Bl[0], Wl[1],Gl[1],Bl[1],
    fA, fB, cA, cB, 216, 7992, 7056, 3, 3, 3, 72, 2664, 2352,
    hk, hv, pkey, pslot, cnt, map, nact, scale, shift, ocnt, obase, olist, P);
  run_stage<7, 64, 128>(stream, 1, Wl[2],Gl[2],Bl[2], Wl[3],Gl[3],Bl[3],
    fB, fA, cB, cA, 72, 2664, 2352, 3, 3, 3, 24, 888, 784,
    hk, hv, pkey, pslot, cnt, map, nact, scale, shift, ocnt, obase, olist, P);
  run_stage<5, 128, 256>(stream, 2, Wl[4],Gl[4],Bl[4], Wl[5],Gl[5],Bl[5],
    fA, fB, cA, cB, 24, 888, 784, 3, 2, 2, 8, 444, 392,
    hk, hv, pkey, pslot, cnt, map, nact, scale, shift, ocnt, obase, olist, P);
  run_stage<3, 256, 384>(stream, 3, Wl[6],Gl[6],Bl[6], Wl[7],Gl[7],Bl[7],
    fB, fA, cB, cA, 8, 444, 392, 2, 2, 2, 4, 222, 196,
    hk, hv, pkey, pslot, cnt, map, nact, scale, shift, ocnt, obase, olist, P);
  run_stage<3, 384, 512>(stream, 4, Wl[8],Gl[8],Bl[8], Wl[9],Gl[9],Bl[9],
    fA, fB, cA, cB, 4, 222, 196, 2, 2, 2, 2, 111, 98,
    hk, hv, pkey, pslot, cnt, map, nact, scale, shift, ocnt, obase, olist, P);

  hipMemsetAsync(d_out, 0, (size_t)out_size * sizeof(float), stream);
  k_out<<<NV*512/256, 256, 0, stream>>>(fB, cB, (float*)d_out, nact + 5);
}

// Round 9
// 795.181 us; speedup vs baseline: 1.1709x; 1.0230x over previous
//
#include <hip/hip_runtime.h>
#include <climits>
#include <cstdint>

#define NV    2048
#define MAXE  344
#define HSIZE 8192
#define HMASK 8191
#define BIGK  LLONG_MAX
#define K3MAX 343
#define MAXP  256
#define PBUDGET (76ull*1024*1024)

__device__ __forceinline__ unsigned hashk(long long k) {
  unsigned long long x = (unsigned long long)k * 0x9E3779B97F4A7C15ull;
  return (unsigned)(x >> 51) & HMASK;
}

// ---------------- init ----------------
__global__ __launch_bounds__(256) void k_init(const float* __restrict__ vf,
    const int* __restrict__ coors, int* __restrict__ cA, float* __restrict__ fA,
    int* __restrict__ nact)
{
  int i = blockIdx.x * 256 + threadIdx.x;
  if (i == 0) nact[0] = NV;
  if (i >= NV) return;
  cA[i*4+0] = coors[i*4+0];
  cA[i*4+1] = coors[i*4+1];
  cA[i*4+2] = coors[i*4+2];
  cA[i*4+3] = coors[i*4+3];
  fA[i] = vf[i];
}

// ---------------- hash ----------------
__global__ __launch_bounds__(256) void k_hclear(long long* __restrict__ hk,
    int* __restrict__ ocnt)
{
  int i = blockIdx.x * 256 + threadIdx.x;
  if (i < HSIZE) hk[i] = -1LL;
  if (i < K3MAX) ocnt[i] = 0;
}

__global__ __launch_bounds__(256) void k_hinsert(const int* __restrict__ c,
    long long* __restrict__ hk, int* __restrict__ hv, const int* __restrict__ nactp,
    int D, int H, int Wd)
{
  int i = blockIdx.x * 256 + threadIdx.x;
  if (i >= NV || i >= *nactp) return;
  long long key = (((long long)c[i*4+0]*D + c[i*4+1])*H + c[i*4+2])*(long long)Wd + c[i*4+3];
  unsigned h = hashk(key);
  while (true) {
    unsigned long long old = atomicCAS((unsigned long long*)&hk[h], ~0ull, (unsigned long long)key);
    if (old == ~0ull) { hv[h] = i; break; }
    h = (h + 1) & HMASK;
  }
}

// ---------------- neighbor hit lists (one wave per site), grouped by offset ----------------
template<int K>
__global__ __launch_bounds__(256) void k_hits(const int* __restrict__ c,
    const long long* __restrict__ hk, const int* __restrict__ hv,
    const int* __restrict__ nactp, int* __restrict__ pslot, int* __restrict__ cnt,
    int* __restrict__ ocnt, int* __restrict__ olist,
    int D, int H, int Wd)
{
  constexpr int K3 = K*K*K, R = K/2, CTR = K3/2;
  const int site = blockIdx.x * 4 + (threadIdx.x >> 6);
  const int lane = threadIdx.x & 63;
  const int nact = *nactp;
  if (site >= NV) return;
  if (site >= nact) { if (lane == 0) cnt[site] = 0; return; }
  const int b = c[site*4+0], d = c[site*4+1], hc = c[site*4+2], w = c[site*4+3];
  int base = 0;
  for (int o0 = 0; o0 < K3; o0 += 64) {
    const int o = o0 + lane;
    int j = -1;
    if (o < K3 && o != CTR) {
      const int dz = o/(K*K) - R, dy = (o/K)%K - R, dx = o%K - R;
      const int nd = d+dz, nh = hc+dy, nw = w+dx;
      if (nd >= 0 && nd < D && nh >= 0 && nh < H && nw >= 0 && nw < Wd) {
        const long long key = (((long long)b*D + nd)*H + nh)*(long long)Wd + nw;
        unsigned hs = hashk(key);
        while (true) {
          const long long kk = hk[hs];
          if (kk == -1LL) break;
          if (kk == key) { j = hv[hs]; break; }
          hs = (hs + 1) & HMASK;
        }
      }
    }
    const unsigned long long m = __ballot(j >= 0);
    if (j >= 0) {
      const int pos = __popcll(m & ((1ull << lane) - 1ull));
      const int p = atomicAdd(&ocnt[o], 1);
      int tag = -1;
      if (p < MAXP) { olist[o * MAXP + p] = (site << 12) | j; tag = (o << 8) | p; }
      pslot[site * MAXE + base + pos] = tag;
    }
    base += __popcll(m);
  }
  if (lane == 0) cnt[site] = base;
}

// ---------------- exclusive scan of per-offset hit counts -> compact slot bases ----------------
__global__ __launch_bounds__(512) void k_oscan(const int* __restrict__ ocnt,
    int* __restrict__ obase)
{
  __shared__ int s[512];
  const int t = threadIdx.x;
  const int v = (t < K3MAX) ? min(ocnt[t], MAXP) : 0;
  s[t] = v;
  __syncthreads();
  for (int d = 1; d < 512; d <<= 1) {
    const int x = (t >= d) ? s[t - d] : 0;
    __syncthreads();
    s[t] += x;
    __syncthreads();
  }
  if (t < K3MAX) obase[t] = s[t] - v;
}

// ---------------- center GEMM, CIN==1: outer product ----------------
template<int COUT>
__global__ __launch_bounds__(256) void k_gemm1(const float* __restrict__ f,
    const float* __restrict__ Wc, float* __restrict__ out)
{
  const int idx = blockIdx.x * 256 + threadIdx.x;
  if (idx >= NV * COUT) return;
  const int i = idx / COUT, c = idx - i * COUT;
  out[idx] = f[i] * Wc[c];
}

// ---------------- dense center GEMM: LDS-tiled, reg-prefetch double buffer ----------------
template<int CIN, int COUT>
__global__ __launch_bounds__(256) void k_gemm(const float* __restrict__ f,
    const float* __restrict__ Wc, float* __restrict__ out)
{
  constexpr int BN = (COUT < 128) ? COUT : 128;
  constexpr int NQ = BN / 4;
  constexpr int TY = 256 / NQ;
  constexpr int BM = 32;
  constexpr int MR = BM / TY;
  constexpr int KT = 32;
  constexpr int NT = CIN / KT;
  constexpr int NCB = COUT / BN;
  constexpr int WLPT = (KT * NQ) / 256;
  __shared__ float as[BM][KT + 1];
  __shared__ float ws[KT][BN];

  const int rb = blockIdx.x / NCB;
  const int cb = blockIdx.x - rb * NCB;
  const int row0 = rb * BM;
  const int col0 = cb * BN;
  const int tid = threadIdx.x;
  const int cq = tid % NQ;
  const int ty = tid / NQ;
  const int la_r = tid >> 3;
  const int la_q = tid & 7;

  const float* __restrict__ fA = f + (size_t)(row0 + la_r) * CIN + la_q * 4;
  const float* __restrict__ fW = Wc + col0;

  float4 aP, wP[WLPT];
  aP = *(const float4*)&fA[0];
  #pragma unroll
  for (int i = 0; i < WLPT; ++i) {
    const int idx = tid + i*256, k = idx / NQ, q = idx - k*NQ;
    wP[i] = *(const float4*)&fW[(size_t)k * COUT + q*4];
  }

  float4 acc[MR];
  #pragma unroll
  for (int i = 0; i < MR; ++i) { acc[i].x=0.f; acc[i].y=0.f; acc[i].z=0.f; acc[i].w=0.f; }

  for (int t = 0; t < NT; ++t) {
    as[la_r][la_q*4+0] = aP.x;
    as[la_r][la_q*4+1] = aP.y;
    as[la_r][la_q*4+2] = aP.z;
    as[la_r][la_q*4+3] = aP.w;
    #pragma unroll
    for (int i = 0; i < WLPT; ++i) {
      const int idx = tid + i*256, k = idx / NQ, q = idx - k*NQ;
      *(float4*)&ws[k][q*4] = wP[i];
    }
    __syncthreads();
    if (t + 1 < NT) {
      const int k0 = (t + 1) * KT;
      aP = *(const float4*)&fA[k0];
      #pragma unroll
      for (int i = 0; i < WLPT; ++i) {
        const int idx = tid + i*256, k = idx / NQ, q = idx - k*NQ;
        wP[i] = *(const float4*)&fW[(size_t)(k0 + k) * COUT + q*4];
      }
    }
    #pragma unroll
    for (int k = 0; k < KT; ++k) {
      const float4 wv = *(const float4*)&ws[k][cq*4];
      #pragma unroll
      for (int i = 0; i < MR; ++i) {
        const float av = as[ty*MR + i][k];
        acc[i].x = fmaf(av, wv.x, acc[i].x);
        acc[i].y = fmaf(av, wv.y, acc[i].y);
        acc[i].z = fmaf(av, wv.z, acc[i].z);
        acc[i].w = fmaf(av, wv.w, acc[i].w);
      }
    }
    __syncthreads();
  }
  #pragma unroll
  for (int i = 0; i < MR; ++i)
    *(float4*)&out[(size_t)(row0 + ty*MR + i) * COUT + col0 + cq*4] = acc[i];
}

// ---------------- legacy pgemm: used only for CIN==1 (layer 0), tiny ----------------
template<int CIN, int COUT>
__global__ __launch_bounds__(256) void k_pgemm(const float* __restrict__ f,
    const float* __restrict__ Wall, float* __restrict__ P,
    const int* __restrict__ ocnt, const int* __restrict__ obase,
    const int* __restrict__ olist)
{
  constexpr int SLOTCAP = (int)(PBUDGET / (COUT*4));
  const int o = blockIdx.x;
  int m = ocnt[o];
  if (m == 0) return;
  if (m > MAXP) m = MAXP;
  const int sbase = obase[o];
  const int tid = threadIdx.x;
  const float* __restrict__ Wo = Wall + (size_t)o * (CIN*COUT);
  for (int p = 0; p < m; ++p) {
    const int j = olist[o*MAXP + p] & 0xFFF;
    const float fv = f[j];   // CIN == 1
    const int slot = sbase + p;
    if (slot < SLOTCAP && tid < COUT)
      P[(size_t)slot*COUT + tid] = fv * Wo[tid];
  }
}

// ---------------- per-(offset, k-chunk) gather-GEMM ----------------
template<int CIN, int COUT, int KSP>
__global__ __launch_bounds__(256) void k_pogemm(const float* __restrict__ f,
    const float* __restrict__ Wall, float* __restrict__ P,
    const int* __restrict__ ocnt, const int* __restrict__ obase,
    const int* __restrict__ olist)
{
  constexpr int KCH = CIN / KSP;
  constexpr int BN = (COUT < 128) ? COUT : 128;
  constexpr int NQ = BN / 4;
  constexpr int TY = 256 / NQ;
  constexpr int BM = 32;
  constexpr int MR = BM / TY;
  constexpr int KT = 32;
  constexpr int NT = KCH / KT;
  constexpr int NCB = COUT / BN;
  constexpr int NRT = MAXP / BM;
  constexpr int WLPT = (KT * NQ) / 256;
  constexpr int SLOTCAP = (int)(PBUDGET / ((size_t)KSP*COUT*4));
  __shared__ float as[BM][KT + 1];
  __shared__ float ws[KT][BN];

  const int o    = blockIdx.x / (NRT * NCB * KSP);
  int rem        = blockIdx.x - o * (NRT * NCB * KSP);
  const int rt   = rem / (NCB * KSP);
  rem           -= rt * (NCB * KSP);
  const int cb   = rem / KSP;
  const int ksp  = rem - cb * KSP;
  int m = ocnt[o];
  if (m > MAXP) m = MAXP;
  const int row0 = rt * BM;
  if (m == 0 || row0 >= m) return;
  const int sbase = obase[o];
  const int col0 = cb * BN;
  const int kch0 = ksp * KCH;
  const int tid = threadIdx.x;
  const int cq = tid % NQ;
  const int ty = tid / NQ;
  const int la_r = tid >> 3;
  const int la_q = tid & 7;

  const int pA = row0 + la_r;
  const int jrow = olist[o*MAXP + ((pA < m) ? pA : row0)] & 0xFFF;
  const float* __restrict__ fA = f + (size_t)jrow * CIN + kch0 + la_q * 4;
  const float* __restrict__ fW = Wall + (size_t)o * (CIN*COUT) + (size_t)kch0 * COUT + col0;

  float4 aP, wP[WLPT];
  aP = *(const float4*)&fA[0];
  #pragma unroll
  for (int i = 0; i < WLPT; ++i) {
    const int idx = tid + i*256, k = idx / NQ, q = idx - k*NQ;
    wP[i] = *(const float4*)&fW[(size_t)k * COUT + q*4];
  }

  float4 acc[MR];
  #pragma unroll
  for (int i = 0; i < MR; ++i) { acc[i].x=0.f; acc[i].y=0.f; acc[i].z=0.f; acc[i].w=0.f; }

  for (int t = 0; t < NT; ++t) {
    as[la_r][la_q*4+0] = aP.x;
    as[la_r][la_q*4+1] = aP.y;
    as[la_r][la_q*4+2] = aP.z;
    as[la_r][la_q*4+3] = aP.w;
    #pragma unroll
    for (int i = 0; i < WLPT; ++i) {
      const int idx = tid + i*256, k = idx / NQ, q = idx - k*NQ;
      *(float4*)&ws[k][q*4] = wP[i];
    }
    __syncthreads();
    if (t + 1 < NT) {
      const int k0 = (t + 1) * KT;
      aP = *(const float4*)&fA[k0];
      #pragma unroll
      for (int i = 0; i < WLPT; ++i) {
        const int idx = tid + i*256, k = idx / NQ, q = idx - k*NQ;
        wP[i] = *(const float4*)&fW[(size_t)(k0 + k) * COUT + q*4];
      }
    }
    #pragma unroll
    for (int k = 0; k < KT; ++k) {
      const float4 wv = *(const float4*)&ws[k][cq*4];
      #pragma unroll
      for (int i = 0; i < MR; ++i) {
        const float av = as[ty*MR + i][k];
        acc[i].x = fmaf(av, wv.x, acc[i].x);
        acc[i].y = fmaf(av, wv.y, acc[i].y);
        acc[i].z = fmaf(av, wv.z, acc[i].z);
        acc[i].w = fmaf(av, wv.w, acc[i].w);
      }
    }
    __syncthreads();
  }
  #pragma unroll
  for (int i = 0; i < MR; ++i) {
    const int p = row0 + ty*MR + i;
    const int slot = sbase + p;
    if (p < m && slot < SLOTCAP)
      *(float4*)&P[((size_t)slot * KSP + ksp) * COUT + col0 + cq*4] = acc[i];
  }
}

// ---------------- phase 2: per-site deterministic sum of partials ----------------
template<int COUT, int KSP>
__global__ __launch_bounds__(256) void k_psum(float* __restrict__ out,
    const float* __restrict__ P, const int* __restrict__ pslot,
    const int* __restrict__ obase, const int* __restrict__ cnt,
    const int* __restrict__ nactp)
{
  constexpr int SLOTCAP = (int)(PBUDGET / ((size_t)KSP*COUT*4));
  const int idx = blockIdx.x * 256 + threadIdx.x;
  const int i = idx / COUT;
  if (i >= *nactp) return;
  const int n = cnt[i];
  if (n == 0) return;
  const int cc = idx - i * COUT;
  float acc = 0.f;
  for (int h = 0; h < n; ++h) {
    const int e = pslot[i * MAXE + h];
    if (e < 0) continue;
    const int slot = obase[e >> 8] + (e & 0xFF);
    if (slot >= SLOTCAP) continue;
    #pragma unroll
    for (int ksp = 0; ksp < KSP; ++ksp)
      acc += P[((size_t)slot * KSP + ksp) * COUT + cc];
  }
  out[idx] += acc;
}

// ---------------- BN stats -> scale/shift ----------------
template<int COUT>
__global__ __launch_bounds__(256) void k_bnstats(const float* __restrict__ x,
    const float* __restrict__ g, const float* __restrict__ b,
    float* __restrict__ scale, float* __restrict__ shift, const int* __restrict__ nactp)
{
  const int c = blockIdx.x;
  const int tid = threadIdx.x;
  double s1 = 0.0, s2 = 0.0;
  for (int r = tid; r < NV; r += 256) {
    const double v = (double)x[r * COUT + c];
    s1 += v; s2 += v * v;
  }
  __shared__ double r1[256], r2[256];
  r1[tid] = s1; r2[tid] = s2;
  __syncthreads();
  for (int off = 128; off > 0; off >>= 1) {
    if (tid < off) { r1[tid] += r1[tid + off]; r2[tid] += r2[tid + off]; }
    __syncthreads();
  }
  if (tid == 0) {
    const double n = (double)(*nactp);
    const double mu = r1[0] / n;
    double var = r2[0] / n - mu * mu;
    if (var < 0.0) var = 0.0;
    const double sc = (double)g[c] / sqrt(var + 1e-4);
    scale[c] = (float)sc;
    shift[c] = (float)((double)b[c] - mu * sc);
  }
}

// ---------------- BN apply + ReLU (in place) ----------------
template<int COUT>
__global__ __launch_bounds__(256) void k_bnrelu(float* __restrict__ x,
    const float* __restrict__ scale, const float* __restrict__ shift,
    const int* __restrict__ nactp)
{
  const int idx = blockIdx.x * 256 + threadIdx.x;
  if (idx >= NV * COUT) return;
  const int i = idx / COUT, c = idx % COUT;
  float v = 0.f;
  if (i < *nactp) {
    const float y = fmaf(x[idx], scale[c], shift[c]);
    v = (y > 0.f) ? y : 0.f;
  }
  x[idx] = v;
}

// ---------------- fused conv-b epilogue: BN+ReLU on x, zero fY, pool keys ----------------
template<int COUT>
__global__ __launch_bounds__(256) void k_bnpool(float* __restrict__ x,
    const float* __restrict__ scale, const float* __restrict__ shift,
    const int* __restrict__ nactp, const int* __restrict__ c,
    long long* __restrict__ pk, float* __restrict__ fYzero,
    int sd, int sh, int sw, int oD, int oH, int oW)
{
  const int idx = blockIdx.x * 256 + threadIdx.x;
  if (idx >= NV * COUT) return;
  const int i = idx / COUT, cc = idx % COUT;
  const int nact = *nactp;
  float v = 0.f;
  if (i < nact) {
    const float y = fmaf(x[idx], scale[cc], shift[cc]);
    v = (y > 0.f) ? y : 0.f;
  }
  x[idx] = v;
  fYzero[idx] = 0.f;
  if (idx < NV) {
    if (idx < nact) {
      const int b = c[idx*4+0];
      const int d = c[idx*4+1] / sd, h = c[idx*4+2] / sh, w = c[idx*4+3] / sw;
      pk[idx] = (((long long)b*oD + d)*oH + h)*(long long)oW + w;
    } else pk[idx] = BIGK;
  }
}

__global__ __launch_bounds__(1024) void k_sortcompact(const long long* __restrict__ pk,
    int* __restrict__ cNew, int* __restrict__ map, int* __restrict__ nactOut,
    int D, int H, int Wd)
{
  __shared__ long long sk[NV];
  __shared__ int si[NV];
  __shared__ int sc[NV];
  __shared__ int s2[NV];
  const int tid = threadIdx.x;
  for (int e = 0; e < 2; ++e) { const int t = tid + e*1024; sk[t] = pk[t]; si[t] = t; }
  __syncthreads();
  for (int k = 2; k <= NV; k <<= 1)
    for (int j = k >> 1; j > 0; j >>= 1) {
      for (int e = 0; e < 2; ++e) {
        const int i = tid + e*1024;
        const int ixj = i ^ j;
        if (ixj > i) {
          const bool up = ((i & k) == 0);
          const long long a = sk[i], bb = sk[ixj];
          const bool sw = up ? (a > bb) : (a < bb);
          if (sw) { sk[i] = bb; sk[ixj] = a; const int t2 = si[i]; si[i] = si[ixj]; si[ixj] = t2; }
        }
      }
      __syncthreads();
    }
  for (int e = 0; e < 2; ++e) {
    const int t = tid + e*1024;
    sc[t] = (sk[t] != BIGK && (t == 0 || sk[t] != sk[t-1])) ? 1 : 0;
  }
  __syncthreads();
  for (int d2 = 1; d2 < NV; d2 <<= 1) {
    for (int e = 0; e < 2; ++e) { const int t = tid + e*1024; s2[t] = sc[t] + ((t >= d2) ? sc[t - d2] : 0); }
    __syncthreads();
    for (int e = 0; e < 2; ++e) { const int t = tid + e*1024; sc[t] = s2[t]; }
    __syncthreads();
  }
  for (int e = 0; e < 2; ++e) {
    const int t = tid + e*1024;
    const long long key = sk[t];
    if (key != BIGK) {
      const int g = sc[t] - 1;
      map[si[t]] = g;
      if (t == 0 || sk[t-1] != key) {
        const int w = (int)(key % Wd);
        long long r = key / Wd;
        const int h = (int)(r % H); r /= H;
        const int d = (int)(r % D);
        const int b = (int)(r / D);
        cNew[g*4+0] = b; cNew[g*4+1] = d; cNew[g*4+2] = h; cNew[g*4+3] = w;
      }
    }
  }
  if (tid == 0) *nactOut = sc[NV-1];
}

template<int C>
__global__ __launch_bounds__(256) void k_pscatter(const float* __restrict__ src,
    float* __restrict__ dst, const int* __restrict__ map, const int* __restrict__ nactp)
{
  const int idx = blockIdx.x * 256 + threadIdx.x;
  const int i = idx / C;
  if (i >= *nactp) return;
  atomicMax((unsigned*)&dst[map[i] * C + (idx % C)], __float_as_uint(src[idx]));
}

// ---------------- output zero (float4 grid-stride) ----------------
__global__ __launch_bounds__(256) void k_zero_out(float4* __restrict__ out, int n4)
{
  const int stride = gridDim.x * 256;
  float4 z; z.x = 0.f; z.y = 0.f; z.z = 0.f; z.w = 0.f;
  for (int i = blockIdx.x * 256 + threadIdx.x; i < n4; i += stride)
    out[i] = z;
}

// ---------------- final dense scatter ----------------
__global__ __launch_bounds__(256) void k_out(const float* __restrict__ f,
    const int* __restrict__ c, float* __restrict__ out, const int* __restrict__ nactp)
{
  const int idx = blockIdx.x * 256 + threadIdx.x;
  const int i = idx >> 9, ch = idx & 511;
  if (i >= *nactp) return;
  const int b = c[i*4+0], d = c[i*4+1], h = c[i*4+2], w = c[i*4+3];
  out[ (((b*512 + ch)*2 + d)*111 + h)*98 + w ] = f[idx];
}

// ---------------- host orchestration ----------------
template<int K, int CIN, int C>
static void run_stage(hipStream_t stream, int s,
    const float* Wa, const float* Ga, const float* Ba,
    const float* Wb, const float* Gb, const float* Bb,
    float* fX, float* fY, int* cX, int* cY,
    int D, int H, int W, int pd, int ph, int pw, int oD, int oH, int oW,
    long long* hk, int* hv, long long* pkey, int* pslot, int* cnt, int* map,
    int* nact, float* scale, float* shift,
    int* ocnt, int* obase, int* olist, float* P)
{
  constexpr int K3 = K*K*K;
  constexpr int CTR = K3/2;
  constexpr int BN   = (C < 128) ? C : 128;
  constexpr int NCB  = C / BN;
  constexpr int NRT  = MAXP / 32;
  constexpr int GEMM_G = (NV / 32) * NCB;
  constexpr int KSPa = (CIN + 127) / 128;
  constexpr int KSPb = (C + 127) / 128;
  const int* na = nact + s;
  k_hclear<<<HSIZE/256, 256, 0, stream>>>(hk, ocnt);
  k_hinsert<<<NV/256, 256, 0, stream>>>(cX, hk, hv, na, D, H, W);
  k_hits<K><<<NV/4, 256, 0, stream>>>(cX, hk, hv, na, pslot, cnt, ocnt, olist, D, H, W);
  k_oscan<<<1, 512, 0, stream>>>(ocnt, obase);

  if constexpr (CIN == 1) {
    k_gemm1<C><<<NV*C/256, 256, 0, stream>>>(fX, Wa + (size_t)CTR*CIN*C, fY);
    k_pgemm<1, C><<<K3, 256, 0, stream>>>(fX, Wa, P, ocnt, obase, olist);
    k_psum<C, 1><<<NV*C/256, 256, 0, stream>>>(fY, P, pslot, obase, cnt, na);
  } else {
    k_gemm<CIN, C><<<GEMM_G, 256, 0, stream>>>(fX, Wa + (size_t)CTR*CIN*C, fY);
    k_pogemm<CIN, C, KSPa><<<K3*NRT*NCB*KSPa, 256, 0, stream>>>(fX, Wa, P, ocnt, obase, olist);
    k_psum<C, KSPa><<<NV*C/256, 256, 0, stream>>>(fY, P, pslot, obase, cnt, na);
  }
  k_bnstats<C><<<C, 256, 0, stream>>>(fY, Ga, Ba, scale, shift, na);
  k_bnrelu<C><<<NV*C/256, 256, 0, stream>>>(fY, scale, shift, na);

  k_gemm<C, C><<<GEMM_G, 256, 0, stream>>>(fY, Wb + (size_t)CTR*C*C, fX);
  k_pogemm<C, C, KSPb><<<K3*NRT*NCB*KSPb, 256, 0, stream>>>(fY, Wb, P, ocnt, obase, olist);
  k_psum<C, KSPb><<<NV*C/256, 256, 0, stream>>>(fX, P, pslot, obase, cnt, na);
  k_bnstats<C><<<C, 256, 0, stream>>>(fX, Gb, Bb, scale, shift, na);
  // fused: bnrelu(fX) + zero(fY) + poolkey
  k_bnpool<C><<<NV*C/256, 256, 0, stream>>>(fX, scale, shift, na, cX, pkey, fY,
      pd, ph, pw, oD, oH, oW);
  k_sortcompact<<<1, 1024, 0, stream>>>(pkey, cY, map, nact + s + 1, oD, oH, oW);
  k_pscatter<C><<<NV*C/256, 256, 0, stream>>>(fX, fY, map, na);
}

extern "C" void kernel_launch(void* const* d_in, const int* in_sizes, int n_in,
                              void* d_out, int out_size, void* d_ws, size_t ws_size,
                              hipStream_t stream)
{
  const float* vf    = (const float*)d_in[0];
  const int*   coors = (const int*)d_in[1];
  const float *Wl[10], *Gl[10], *Bl[10];
  for (int i = 0; i < 10; ++i) {
    Wl[i] = (const float*)d_in[3 + 3*i];
    Gl[i] = (const float*)d_in[4 + 3*i];
    Bl[i] = (const float*)d_in[5 + 3*i];
  }

  char* p = (char*)d_ws;
  auto alloc = [&](size_t bytes) { char* q = p; p += (bytes + 255) & ~(size_t)255; return q; };
  float*     fB    = (float*)    alloc((size_t)NV*512*4);
  long long* hk    = (long long*)alloc((size_t)HSIZE*8);
  long long* pkey  = (long long*)alloc((size_t)NV*8);
  int*       hv    = (int*)      alloc((size_t)HSIZE*4);
  int*       cA    = (int*)      alloc((size_t)NV*4*4);
  int*       cB    = (int*)      alloc((size_t)NV*4*4);
  int*       pslot = (int*)      alloc((size_t)NV*MAXE*4);
  int*       cnt   = (int*)      alloc((size_t)NV*4);
  int*       map   = (int*)      alloc((size_t)NV*4);
  int*       nact  = (int*)      alloc(8*4);
  float*     scale = (float*)    alloc(512*4);
  float*     shift = (float*)    alloc(512*4);
  int*       ocnt  = (int*)      alloc((size_t)K3MAX*4);
  int*       obase = (int*)      alloc((size_t)K3MAX*4);

  // scratch aliased into d_out (89 MB); all dead before the final zero
  float* fA    = (float*)d_out;                                   // 4 MB
  int*   olist = (int*)  ((char*)d_out + (size_t)8*1024*1024);    // 343*256*4 = 351 KB
  float* P     = (float*)((char*)d_out + (size_t)9*1024*1024);    // 76 MB budget (SLOTCAP-guarded)

  k_init<<<NV/256, 256, 0, stream>>>(vf, coors, cA, fA, nact);

  run_stage<7, 1, 64>  (stream, 0, Wl[0],Gl[0],Bl[0], Wl[1],Gl[1],Bl[1],
    fA, fB, cA, cB, 216, 7992, 7056, 3, 3, 3, 72, 2664, 2352,
    hk, hv, pkey, pslot, cnt, map, nact, scale, shift, ocnt, obase, olist, P);
  run_stage<7, 64, 128>(stream, 1, Wl[2],Gl[2],Bl[2], Wl[3],Gl[3],Bl[3],
    fB, fA, cB, cA, 72, 2664, 2352, 3, 3, 3, 24, 888, 784,
    hk, hv, pkey, pslot, cnt, map, nact, scale, shift, ocnt, obase, olist, P);
  run_stage<5, 128, 256>(stream, 2, Wl[4],Gl[4],Bl[4], Wl[5],Gl[5],Bl[5],
    fA, fB, cA, cB, 24, 888, 784, 3, 2, 2, 8, 444, 392,
    hk, hv, pkey, pslot, cnt, map, nact, scale, shift, ocnt, obase, olist, P);
  run_stage<3, 256, 384>(stream, 3, Wl[6],Gl[6],Bl[6], Wl[7],Gl[7],Bl[7],
    fB, fA, cB, cA, 8, 444, 392, 2, 2, 2, 4, 222, 196,
    hk, hv, pkey, pslot, cnt, map, nact, scale, shift, ocnt, obase, olist, P);
  run_stage<3, 384, 512>(stream, 4, Wl[8],Gl[8],Bl[8], Wl[9],Gl[9],Bl[9],
    fA, fB, cA, cB, 4, 222, 196, 2, 2, 2, 2, 111, 98,
    hk, hv, pkey, pslot, cnt, map, nact, scale, shift, ocnt, obase, olist, P);

  k_zero_out<<<2048, 256, 0, stream>>>((float4*)d_out, out_size / 4);
  k_out<<<NV*512/256, 256, 0, stream>>>(fB, cB, (float*)d_out, nact + 5);
}

// Round 10
// 752.467 us; speedup vs baseline: 1.2374x; 1.0568x over previous
//
#include <hip/hip_runtime.h>
#include <climits>
#include <cstdint>

#define NV    2048
#define MAXE  344
#define HSIZE 8192
#define HMASK 8191
#define BIGK  LLONG_MAX
#define K3MAX 343
#define MAXP  256
#define PBUDGET (76ull*1024*1024)

__device__ __forceinline__ unsigned hashk(long long k) {
  unsigned long long x = (unsigned long long)k * 0x9E3779B97F4A7C15ull;
  return (unsigned)(x >> 51) & HMASK;
}

// ---------------- init + hash clear (fused) ----------------
__global__ __launch_bounds__(256) void k_init(const float* __restrict__ vf,
    const int* __restrict__ coors, int* __restrict__ cA, float* __restrict__ fA,
    int* __restrict__ nact, long long* __restrict__ hk, int* __restrict__ ocnt)
{
  const int bid = blockIdx.x;
  if (bid < 8) {
    const int i = bid * 256 + threadIdx.x;
    if (i == 0) nact[0] = NV;
    if (i >= NV) return;
    cA[i*4+0] = coors[i*4+0];
    cA[i*4+1] = coors[i*4+1];
    cA[i*4+2] = coors[i*4+2];
    cA[i*4+3] = coors[i*4+3];
    fA[i] = vf[i];
  } else {
    const int i = (bid - 8) * 256 + threadIdx.x;
    if (i < HSIZE) hk[i] = -1LL;
    if (i < K3MAX) ocnt[i] = 0;
  }
}

__global__ __launch_bounds__(256) void k_hinsert(const int* __restrict__ c,
    long long* __restrict__ hk, int* __restrict__ hv, const int* __restrict__ nactp,
    int D, int H, int Wd)
{
  int i = blockIdx.x * 256 + threadIdx.x;
  if (i >= NV || i >= *nactp) return;
  long long key = (((long long)c[i*4+0]*D + c[i*4+1])*H + c[i*4+2])*(long long)Wd + c[i*4+3];
  unsigned h = hashk(key);
  while (true) {
    unsigned long long old = atomicCAS((unsigned long long*)&hk[h], ~0ull, (unsigned long long)key);
    if (old == ~0ull) { hv[h] = i; break; }
    h = (h + 1) & HMASK;
  }
}

// ---------------- neighbor hit lists (one wave per site), grouped by offset ----------------
template<int K>
__global__ __launch_bounds__(256) void k_hits(const int* __restrict__ c,
    const long long* __restrict__ hk, const int* __restrict__ hv,
    const int* __restrict__ nactp, int* __restrict__ pslot, int* __restrict__ cnt,
    int* __restrict__ ocnt, int* __restrict__ olist,
    int D, int H, int Wd)
{
  constexpr int K3 = K*K*K, R = K/2, CTR = K3/2;
  const int site = blockIdx.x * 4 + (threadIdx.x >> 6);
  const int lane = threadIdx.x & 63;
  const int nact = *nactp;
  if (site >= NV) return;
  if (site >= nact) { if (lane == 0) cnt[site] = 0; return; }
  const int b = c[site*4+0], d = c[site*4+1], hc = c[site*4+2], w = c[site*4+3];
  int base = 0;
  for (int o0 = 0; o0 < K3; o0 += 64) {
    const int o = o0 + lane;
    int j = -1;
    if (o < K3 && o != CTR) {
      const int dz = o/(K*K) - R, dy = (o/K)%K - R, dx = o%K - R;
      const int nd = d+dz, nh = hc+dy, nw = w+dx;
      if (nd >= 0 && nd < D && nh >= 0 && nh < H && nw >= 0 && nw < Wd) {
        const long long key = (((long long)b*D + nd)*H + nh)*(long long)Wd + nw;
        unsigned hs = hashk(key);
        while (true) {
          const long long kk = hk[hs];
          if (kk == -1LL) break;
          if (kk == key) { j = hv[hs]; break; }
          hs = (hs + 1) & HMASK;
        }
      }
    }
    const unsigned long long m = __ballot(j >= 0);
    if (j >= 0) {
      const int pos = __popcll(m & ((1ull << lane) - 1ull));
      const int p = atomicAdd(&ocnt[o], 1);
      int tag = -1;
      if (p < MAXP) { olist[o * MAXP + p] = (site << 12) | j; tag = (o << 8) | p; }
      pslot[site * MAXE + base + pos] = tag;
    }
    base += __popcll(m);
  }
  if (lane == 0) cnt[site] = base;
}

// ---------------- exclusive scan of per-offset hit counts ----------------
__global__ __launch_bounds__(512) void k_oscan(const int* __restrict__ ocnt,
    int* __restrict__ obase)
{
  __shared__ int s[512];
  const int t = threadIdx.x;
  const int v = (t < K3MAX) ? min(ocnt[t], MAXP) : 0;
  s[t] = v;
  __syncthreads();
  for (int d = 1; d < 512; d <<= 1) {
    const int x = (t >= d) ? s[t - d] : 0;
    __syncthreads();
    s[t] += x;
    __syncthreads();
  }
  if (t < K3MAX) obase[t] = s[t] - v;
}

// ---------------- fused center + per-offset gather GEMM ----------------
// blocks [0, NG): center GEMM  out = f @ W[ctr]
// blocks [NG, ..): per-(offset, row-tile, col-block, k-chunk) partials into P
template<int CIN, int COUT, int KSP>
__global__ __launch_bounds__(256) void k_cgemm(const float* __restrict__ f,
    const float* __restrict__ Wall, int ctr,
    float* __restrict__ outC, float* __restrict__ P,
    const int* __restrict__ ocnt, const int* __restrict__ obase,
    const int* __restrict__ olist)
{
  constexpr int BN = (COUT < 128) ? COUT : 128;
  constexpr int NQ = BN / 4;
  constexpr int TY = 256 / NQ;
  constexpr int BM = 32;
  constexpr int MR = BM / TY;
  constexpr int KT = 32;
  constexpr int NCB = COUT / BN;
  constexpr int NRT = MAXP / BM;
  constexpr int KCH = CIN / KSP;
  constexpr int NT_C = CIN / KT;
  constexpr int NT_P = KCH / KT;
  constexpr int NG = (NV / BM) * NCB;
  constexpr int WLPT = (KT * NQ) / 256;
  constexpr int SLOTCAP = (int)(PBUDGET / ((size_t)KSP*COUT*4));
  __shared__ float as[BM][KT + 1];
  __shared__ float ws[KT][BN];

  const int tid = threadIdx.x;
  const int cq = tid % NQ;
  const int ty = tid / NQ;
  const int la_r = tid >> 3;
  const int la_q = tid & 7;

  bool po;
  int row0, col0, kch0, nt, m, sbase = 0, ksp = 0, o = 0;
  if (blockIdx.x < NG) {
    po = false;
    const int rb = blockIdx.x / NCB, cb = blockIdx.x - rb * NCB;
    row0 = rb * BM; col0 = cb * BN; kch0 = 0; nt = NT_C; m = BM;
  } else {
    po = true;
    int bid = blockIdx.x - NG;
    o = bid / (NRT * NCB * KSP);
    int rem = bid - o * (NRT * NCB * KSP);
    const int rt = rem / (NCB * KSP); rem -= rt * (NCB * KSP);
    const int cb = rem / KSP; ksp = rem - cb * KSP;
    m = min(ocnt[o], MAXP);
    row0 = rt * BM;
    if (m == 0 || row0 >= m) return;
    sbase = obase[o]; col0 = cb * BN; kch0 = ksp * KCH; nt = NT_P;
  }

  const float* __restrict__ fW = po
    ? (Wall + (size_t)o   * (CIN*COUT) + (size_t)kch0 * COUT + col0)
    : (Wall + (size_t)ctr * (CIN*COUT) + col0);
  int grow;
  if (!po) grow = row0 + la_r;
  else { const int pA = row0 + la_r; grow = olist[o*MAXP + ((pA < m) ? pA : row0)] & 0xFFF; }
  const float* __restrict__ fA = f + (size_t)grow * CIN + kch0 + la_q * 4;

  float4 aP, wP[WLPT];
  aP = *(const float4*)&fA[0];
  #pragma unroll
  for (int i = 0; i < WLPT; ++i) {
    const int idx = tid + i*256, k = idx / NQ, q = idx - k*NQ;
    wP[i] = *(const float4*)&fW[(size_t)k * COUT + q*4];
  }

  float4 acc[MR];
  #pragma unroll
  for (int i = 0; i < MR; ++i) { acc[i].x=0.f; acc[i].y=0.f; acc[i].z=0.f; acc[i].w=0.f; }

  for (int t = 0; t < nt; ++t) {
    as[la_r][la_q*4+0] = aP.x;
    as[la_r][la_q*4+1] = aP.y;
    as[la_r][la_q*4+2] = aP.z;
    as[la_r][la_q*4+3] = aP.w;
    #pragma unroll
    for (int i = 0; i < WLPT; ++i) {
      const int idx = tid + i*256, k = idx / NQ, q = idx - k*NQ;
      *(float4*)&ws[k][q*4] = wP[i];
    }
    __syncthreads();
    if (t + 1 < nt) {
      const int k0 = (t + 1) * KT;
      aP = *(const float4*)&fA[k0];
      #pragma unroll
      for (int i = 0; i < WLPT; ++i) {
        const int idx = tid + i*256, k = idx / NQ, q = idx - k*NQ;
        wP[i] = *(const float4*)&fW[(size_t)(k0 + k) * COUT + q*4];
      }
    }
    #pragma unroll
    for (int k = 0; k < KT; ++k) {
      const float4 wv = *(const float4*)&ws[k][cq*4];
      #pragma unroll
      for (int i = 0; i < MR; ++i) {
        const float av = as[ty*MR + i][k];
        acc[i].x = fmaf(av, wv.x, acc[i].x);
        acc[i].y = fmaf(av, wv.y, acc[i].y);
        acc[i].z = fmaf(av, wv.z, acc[i].z);
        acc[i].w = fmaf(av, wv.w, acc[i].w);
      }
    }
    __syncthreads();
  }
  if (!po) {
    #pragma unroll
    for (int i = 0; i < MR; ++i)
      *(float4*)&outC[(size_t)(row0 + ty*MR + i) * COUT + col0 + cq*4] = acc[i];
  } else {
    #pragma unroll
    for (int i = 0; i < MR; ++i) {
      const int p = row0 + ty*MR + i;
      const int slot = sbase + p;
      if (p < m && slot < SLOTCAP)
        *(float4*)&P[((size_t)slot * KSP + ksp) * COUT + col0 + cq*4] = acc[i];
    }
  }
}

// ---------------- stage-0 conv-a (CIN==1): outer product + per-offset partials ----------------
template<int COUT>
__global__ __launch_bounds__(256) void k_cgemm1(const float* __restrict__ f,
    const float* __restrict__ Wall, int ctr,
    float* __restrict__ outC, float* __restrict__ P,
    const int* __restrict__ ocnt, const int* __restrict__ obase,
    const int* __restrict__ olist)
{
  constexpr int NG = NV * COUT / 256;
  constexpr int SLOTCAP = (int)(PBUDGET / (COUT*4));
  const int tid = threadIdx.x;
  if (blockIdx.x < NG) {
    const int idx = blockIdx.x * 256 + tid;
    const int i = idx / COUT, c = idx - i * COUT;
    outC[idx] = f[i] * Wall[(size_t)ctr * COUT + c];
  } else {
    const int o = blockIdx.x - NG;
    int m = ocnt[o];
    if (m == 0) return;
    if (m > MAXP) m = MAXP;
    const int sbase = obase[o];
    const float* __restrict__ Wo = Wall + (size_t)o * COUT;
    for (int p = 0; p < m; ++p) {
      const int j = olist[o*MAXP + p] & 0xFFF;
      const int slot = sbase + p;
      if (slot < SLOTCAP && tid < COUT)
        P[(size_t)slot*COUT + tid] = f[j] * Wo[tid];
    }
  }
}

// ---------------- fused psum + BN stats + BN-ReLU (+ pool prep) ----------------
// One block per column c. Preserves psum's h/ksp order and bnstats' row order.
template<int COUT, int KSP, bool POOL>
__global__ __launch_bounds__(256) void k_bn(float* __restrict__ x,
    const float* __restrict__ P, const int* __restrict__ pslot,
    const int* __restrict__ obase, const int* __restrict__ cnt,
    const float* __restrict__ g, const float* __restrict__ b,
    const int* __restrict__ nactp,
    const int* __restrict__ co, long long* __restrict__ pk, float* __restrict__ fY,
    int sd, int sh, int sw, int oD, int oH, int oW)
{
  constexpr int RPT = NV / 256;
  constexpr int SLOTCAP = (int)(PBUDGET / ((size_t)KSP*COUT*4));
  const int c = blockIdx.x;
  const int tid = threadIdx.x;
  const int nact = *nactp;
  float v[RPT];
  double s1 = 0.0, s2 = 0.0;
  #pragma unroll
  for (int rr = 0; rr < RPT; ++rr) {
    const int r = rr * 256 + tid;
    float vv = x[(size_t)r * COUT + c];
    if (r < nact) {
      const int n = cnt[r];
      float acc = 0.f;
      for (int h = 0; h < n; ++h) {
        const int e = pslot[r * MAXE + h];
        if (e < 0) continue;
        const int slot = obase[e >> 8] + (e & 0xFF);
        if (slot >= SLOTCAP) continue;
        #pragma unroll
        for (int ksp = 0; ksp < KSP; ++ksp)
          acc += P[((size_t)slot * KSP + ksp) * COUT + c];
      }
      vv += acc;
    }
    v[rr] = vv;
    s1 += (double)vv;
    s2 += (double)vv * (double)vv;
  }
  __shared__ double r1[256], r2[256];
  __shared__ float ss[2];
  r1[tid] = s1; r2[tid] = s2;
  __syncthreads();
  for (int off = 128; off > 0; off >>= 1) {
    if (tid < off) { r1[tid] += r1[tid + off]; r2[tid] += r2[tid + off]; }
    __syncthreads();
  }
  if (tid == 0) {
    const double n = (double)nact;
    const double mu = r1[0] / n;
    double var = r2[0] / n - mu * mu;
    if (var < 0.0) var = 0.0;
    const double sc = (double)g[c] / sqrt(var + 1e-4);
    ss[0] = (float)sc;
    ss[1] = (float)((double)b[c] - mu * sc);
  }
  __syncthreads();
  const float scale = ss[0], shift = ss[1];
  #pragma unroll
  for (int rr = 0; rr < RPT; ++rr) {
    const int r = rr * 256 + tid;
    float o_ = 0.f;
    if (r < nact) {
      const float y = fmaf(v[rr], scale, shift);
      o_ = (y > 0.f) ? y : 0.f;
    }
    x[(size_t)r * COUT + c] = o_;
    if (POOL) fY[(size_t)r * COUT + c] = 0.f;
  }
  if (POOL && c == 0) {
    #pragma unroll
    for (int rr = 0; rr < RPT; ++rr) {
      const int i = rr * 256 + tid;
      if (i < nact) {
        const int bb = co[i*4+0];
        const int d = co[i*4+1] / sd, h = co[i*4+2] / sh, w = co[i*4+3] / sw;
        pk[i] = (((long long)bb*oD + d)*oH + h)*(long long)oW + w;
      } else pk[i] = BIGK;
    }
  }
}

__global__ __launch_bounds__(1024) void k_sortcompact(const long long* __restrict__ pk,
    int* __restrict__ cNew, int* __restrict__ map, int* __restrict__ nactOut,
    int D, int H, int Wd)
{
  __shared__ long long sk[NV];
  __shared__ int si[NV];
  __shared__ int sc[NV];
  __shared__ int s2[NV];
  const int tid = threadIdx.x;
  for (int e = 0; e < 2; ++e) { const int t = tid + e*1024; sk[t] = pk[t]; si[t] = t; }
  __syncthreads();
  for (int k = 2; k <= NV; k <<= 1)
    for (int j = k >> 1; j > 0; j >>= 1) {
      for (int e = 0; e < 2; ++e) {
        const int i = tid + e*1024;
        const int ixj = i ^ j;
        if (ixj > i) {
          const bool up = ((i & k) == 0);
          const long long a = sk[i], bb = sk[ixj];
          const bool sw = up ? (a > bb) : (a < bb);
          if (sw) { sk[i] = bb; sk[ixj] = a; const int t2 = si[i]; si[i] = si[ixj]; si[ixj] = t2; }
        }
      }
      __syncthreads();
    }
  for (int e = 0; e < 2; ++e) {
    const int t = tid + e*1024;
    sc[t] = (sk[t] != BIGK && (t == 0 || sk[t] != sk[t-1])) ? 1 : 0;
  }
  __syncthreads();
  for (int d2 = 1; d2 < NV; d2 <<= 1) {
    for (int e = 0; e < 2; ++e) { const int t = tid + e*1024; s2[t] = sc[t] + ((t >= d2) ? sc[t - d2] : 0); }
    __syncthreads();
    for (int e = 0; e < 2; ++e) { const int t = tid + e*1024; sc[t] = s2[t]; }
    __syncthreads();
  }
  for (int e = 0; e < 2; ++e) {
    const int t = tid + e*1024;
    const long long key = sk[t];
    if (key != BIGK) {
      const int gi = sc[t] - 1;
      map[si[t]] = gi;
      if (t == 0 || sk[t-1] != key) {
        const int w = (int)(key % Wd);
        long long r = key / Wd;
        const int h = (int)(r % H); r /= H;
        const int d = (int)(r % D);
        const int b = (int)(r / D);
        cNew[gi*4+0] = b; cNew[gi*4+1] = d; cNew[gi*4+2] = h; cNew[gi*4+3] = w;
      }
    }
  }
  if (tid == 0) *nactOut = sc[NV-1];
}

// ---------------- fused pool-scatter + next-stage hash clear ----------------
template<int C>
__global__ __launch_bounds__(256) void k_pscl(const float* __restrict__ src,
    float* __restrict__ dst, const int* __restrict__ map, const int* __restrict__ nactp,
    long long* __restrict__ hk, int* __restrict__ ocnt)
{
  constexpr int GPS = NV * C / 256;
  if (blockIdx.x < GPS) {
    const int idx = blockIdx.x * 256 + threadIdx.x;
    const int i = idx / C;
    if (i >= *nactp) return;
    atomicMax((unsigned*)&dst[map[i] * C + (idx % C)], __float_as_uint(src[idx]));
  } else {
    const int i = (blockIdx.x - GPS) * 256 + threadIdx.x;
    if (i < HSIZE) hk[i] = -1LL;
    if (i < K3MAX) ocnt[i] = 0;
  }
}

// ---------------- output zero (float4 grid-stride) ----------------
__global__ __launch_bounds__(256) void k_zero_out(float4* __restrict__ out, int n4)
{
  const int stride = gridDim.x * 256;
  float4 z; z.x = 0.f; z.y = 0.f; z.z = 0.f; z.w = 0.f;
  for (int i = blockIdx.x * 256 + threadIdx.x; i < n4; i += stride)
    out[i] = z;
}

// ---------------- final dense scatter ----------------
__global__ __launch_bounds__(256) void k_out(const float* __restrict__ f,
    const int* __restrict__ c, float* __restrict__ out, const int* __restrict__ nactp)
{
  const int idx = blockIdx.x * 256 + threadIdx.x;
  const int i = idx >> 9, ch = idx & 511;
  if (i >= *nactp) return;
  const int b = c[i*4+0], d = c[i*4+1], h = c[i*4+2], w = c[i*4+3];
  out[ (((b*512 + ch)*2 + d)*111 + h)*98 + w ] = f[idx];
}

// ---------------- host orchestration ----------------
template<int K, int CIN, int C>
static void run_stage(hipStream_t stream, int s,
    const float* Wa, const float* Ga, const float* Ba,
    const float* Wb, const float* Gb, const float* Bb,
    float* fX, float* fY, int* cX, int* cY,
    int D, int H, int W, int pd, int ph, int pw, int oD, int oH, int oW,
    long long* hk, int* hv, long long* pkey, int* pslot, int* cnt, int* map,
    int* nact, int* ocnt, int* obase, int* olist, float* P)
{
  constexpr int K3 = K*K*K;
  constexpr int CTR = K3/2;
  constexpr int BN   = (C < 128) ? C : 128;
  constexpr int NCB  = C / BN;
  constexpr int NRT  = MAXP / 32;
  constexpr int NG   = (NV / 32) * NCB;
  constexpr int KSPa = (CIN + 127) / 128;
  constexpr int KSPb = (C + 127) / 128;
  const int* na = nact + s;

  k_hinsert<<<NV/256, 256, 0, stream>>>(cX, hk, hv, na, D, H, W);
  k_hits<K><<<NV/4, 256, 0, stream>>>(cX, hk, hv, na, pslot, cnt, ocnt, olist, D, H, W);
  k_oscan<<<1, 512, 0, stream>>>(ocnt, obase);

  if constexpr (CIN == 1)
    k_cgemm1<C><<<NV*C/256 + K3, 256, 0, stream>>>(fX, Wa, CTR, fY, P, ocnt, obase, olist);
  else
    k_cgemm<CIN, C, KSPa><<<NG + K3*NRT*NCB*KSPa, 256, 0, stream>>>(fX, Wa, CTR, fY, P, ocnt, obase, olist);
  k_bn<C, KSPa, false><<<C, 256, 0, stream>>>(fY, P, pslot, obase, cnt, Ga, Ba, na,
      cX, pkey, fX, pd, ph, pw, oD, oH, oW);

  k_cgemm<C, C, KSPb><<<NG + K3*NRT*NCB*KSPb, 256, 0, stream>>>(fY, Wb, CTR, fX, P, ocnt, obase, olist);
  k_bn<C, KSPb, true><<<C, 256, 0, stream>>>(fX, P, pslot, obase, cnt, Gb, Bb, na,
      cX, pkey, fY, pd, ph, pw, oD, oH, oW);

  k_sortcompact<<<1, 1024, 0, stream>>>(pkey, cY, map, nact + s + 1, oD, oH, oW);
  k_pscl<C><<<NV*C/256 + HSIZE/256, 256, 0, stream>>>(fX, fY, map, na, hk, ocnt);
}

extern "C" void kernel_launch(void* const* d_in, const int* in_sizes, int n_in,
                              void* d_out, int out_size, void* d_ws, size_t ws_size,
                              hipStream_t stream)
{
  const float* vf    = (const float*)d_in[0];
  const int*   coors = (const int*)d_in[1];
  const float *Wl[10], *Gl[10], *Bl[10];
  for (int i = 0; i < 10; ++i) {
    Wl[i] = (const float*)d_in[3 + 3*i];
    Gl[i] = (const float*)d_in[4 + 3*i];
    Bl[i] = (const float*)d_in[5 + 3*i];
  }

  char* p = (char*)d_ws;
  auto alloc = [&](size_t bytes) { char* q = p; p += (bytes + 255) & ~(size_t)255; return q; };
  float*     fB    = (float*)    alloc((size_t)NV*512*4);
  long long* hk    = (long long*)alloc((size_t)HSIZE*8);
  long long* pkey  = (long long*)alloc((size_t)NV*8);
  int*       hv    = (int*)      alloc((size_t)HSIZE*4);
  int*       cA    = (int*)      alloc((size_t)NV*4*4);
  int*       cB    = (int*)      alloc((size_t)NV*4*4);
  int*       pslot = (int*)      alloc((size_t)NV*MAXE*4);
  int*       cnt   = (int*)      alloc((size_t)NV*4);
  int*       map   = (int*)      alloc((size_t)NV*4);
  int*       nact  = (int*)      alloc(8*4);
  int*       ocnt  = (int*)      alloc((size_t)K3MAX*4);
  int*       obase = (int*)      alloc((size_t)K3MAX*4);

  // scratch aliased into d_out (89 MB); all dead before the final zero
  float* fA    = (float*)d_out;                                   // 4 MB
  int*   olist = (int*)  ((char*)d_out + (size_t)8*1024*1024);    // 343*256*4 = 351 KB
  float* P     = (float*)((char*)d_out + (size_t)9*1024*1024);    // 76 MB budget (SLOTCAP-guarded)

  k_init<<<40, 256, 0, stream>>>(vf, coors, cA, fA, nact, hk, ocnt);

  run_stage<7, 1, 64>  (stream, 0, Wl[0],Gl[0],Bl[0], Wl[1],Gl[1],Bl[1],
    fA, fB, cA, cB, 216, 7992, 7056, 3, 3, 3, 72, 2664, 2352,
    hk, hv, pkey, pslot, cnt, map, nact, ocnt, obase, olist, P);
  run_stage<7, 64, 128>(stream, 1, Wl[2],Gl[2],Bl[2], Wl[3],Gl[3],Bl[3],
    fB, fA, cB, cA, 72, 2664, 2352, 3, 3, 3, 24, 888, 784,
    hk, hv, pkey, pslot, cnt, map, nact, ocnt, obase, olist, P);
  run_stage<5, 128, 256>(stream, 2, Wl[4],Gl[4],Bl[4], Wl[5],Gl[5],Bl[5],
    fA, fB, cA, cB, 24, 888, 784, 3, 2, 2, 8, 444, 392,
    hk, hv, pkey, pslot, cnt, map, nact, ocnt, obase, olist, P);
  run_stage<3, 256, 384>(stream, 3, Wl[6],Gl[6],Bl[6], Wl[7],Gl[7],Bl[7],
    fB, fA, cB, cA, 8, 444, 392, 2, 2, 2, 4, 222, 196,
    hk, hv, pkey, pslot, cnt, map, nact, ocnt, obase, olist, P);
  run_stage<3, 384, 512>(stream, 4, Wl[8],Gl[8],Bl[8], Wl[9],Gl[9],Bl[9],
    fA, fB, cA, cB, 4, 222, 196, 2, 2, 2, 2, 111, 98,
    hk, hv, pkey, pslot, cnt, map, nact, ocnt, obase, olist, P);

  k_zero_out<<<2048, 256, 0, stream>>>((float4*)d_out, out_size / 4);
  k_out<<<NV*512/256, 256, 0, stream>>>(fB, cB, (float*)d_out, nact + 5);
}